// Round 5
// baseline (1262.488 us; speedup 1.0000x reference)
//
#include <hip/hip_runtime.h>
#include <math.h>

#define S   30
#define FD  200
#define TT  1024
#define BB  1024
#define NC  7

// ---- workspace layout (float offsets), overlaid by live range ----
#define OFS_C1   0ull
#define OFS_F2   31457280ull
#define OFS_AF   0ull
#define OFS_GV   921600ull
#define OFS_GH   10137600ull
#define OFS_WCH  19353600ull
#define OFS_WFT  19384320ull
#define OFS_R    19691520ull   // 3*1024*30*100 floats (inside dead C1 region)

// ================= K1: conv1 + relu -> C1 =================
__global__ __launch_bounds__(256) void k_conv1(
    const float* __restrict__ x,
    const float* __restrict__ Wc1, const float* __restrict__ bc1,
    float* __restrict__ C1) {
    const int c = blockIdx.x, b = blockIdx.y;
    const int t = threadIdx.x;
    const int t0 = c * 256;
    __shared__ float xb[S * 258];
    __shared__ float w1l[90 * 32];
    for (int idx = t; idx < 2700; idx += 256) {
        int so = idx / 90, r = idx % 90;
        w1l[r * 32 + so] = Wc1[idx];
    }
    for (int idx = t; idx < 180; idx += 256) {
        int r = idx >> 1, z = idx & 1;
        w1l[r * 32 + 30 + z] = 0.f;
    }
    for (int idx = t; idx < S * 64; idx += 256) {
        int s = idx >> 6, u = idx & 63;
        float4 v = *(const float4*)(x + (size_t)(b * S + s) * TT + t0 + 4 * u);
        float* d = xb + s * 258 + 1 + 4 * u;
        d[0] = v.x; d[1] = v.y; d[2] = v.z; d[3] = v.w;
    }
    if (t < 60) {
        int s = t % S;
        if (t < S) {
            int gt = t0 - 1;
            xb[s * 258] = (gt >= 0) ? x[(size_t)(b * S + s) * TT + gt] : 0.f;
        } else {
            int gt = t0 + 256;
            xb[s * 258 + 257] = (gt < TT) ? x[(size_t)(b * S + s) * TT + gt] : 0.f;
        }
    }
    __syncthreads();
    float acc[32];
#pragma unroll
    for (int so = 0; so < 32; so++) acc[so] = (so < S) ? bc1[so] : 0.f;
    for (int si = 0; si < S; si++) {
        float v0 = xb[si * 258 + t];
        float v1 = xb[si * 258 + t + 1];
        float v2 = xb[si * 258 + t + 2];
        const float* wr = w1l + si * 96;
#pragma unroll
        for (int u = 0; u < 8; u++) {
            float4 w0 = *(const float4*)(wr + 4 * u);
            float4 w1 = *(const float4*)(wr + 32 + 4 * u);
            float4 w2 = *(const float4*)(wr + 64 + 4 * u);
            acc[4 * u + 0] = fmaf(w0.x, v0, fmaf(w1.x, v1, fmaf(w2.x, v2, acc[4 * u + 0])));
            acc[4 * u + 1] = fmaf(w0.y, v0, fmaf(w1.y, v1, fmaf(w2.y, v2, acc[4 * u + 1])));
            acc[4 * u + 2] = fmaf(w0.z, v0, fmaf(w1.z, v1, fmaf(w2.z, v2, acc[4 * u + 2])));
            acc[4 * u + 3] = fmaf(w0.w, v0, fmaf(w1.w, v1, fmaf(w2.w, v2, acc[4 * u + 3])));
        }
    }
#pragma unroll
    for (int so = 0; so < 32; so++) {
        if (so < S)
            C1[(size_t)(b * S + so) * TT + t0 + t] = fmaxf(acc[so], 0.f);
    }
}

// ---------- FMA tile helpers ----------
#define FMA4(av, wv, accm)                           \
    {                                                \
        accm[0] = fmaf(av, (wv).x, accm[0]);         \
        accm[1] = fmaf(av, (wv).y, accm[1]);         \
        accm[2] = fmaf(av, (wv).z, accm[2]);         \
        accm[3] = fmaf(av, (wv).w, accm[3]);         \
    }

__device__ inline void fma_tile8(const float4 a0, const float4 a1,
                                 const float4 w[8], float accm[4]) {
    FMA4(a0.x, w[0], accm); FMA4(a0.y, w[1], accm);
    FMA4(a0.z, w[2], accm); FMA4(a0.w, w[3], accm);
    FMA4(a1.x, w[4], accm); FMA4(a1.y, w[5], accm);
    FMA4(a1.z, w[6], accm); FMA4(a1.w, w[7], accm);
}

template<int RPT>
__device__ inline void zacc(float acc[][4]) {
#pragma unroll
    for (int m = 0; m < RPT; m++)
#pragma unroll
        for (int q = 0; q < 4; q++) acc[m][q] = 0.f;
}

__device__ inline void zacc8(float a[3][8]) {
#pragma unroll
    for (int m = 0; m < 3; m++)
#pragma unroll
        for (int j = 0; j < 8; j++) a[m][j] = 0.f;
}

// ---------- gemm_w8: X(LDS) @ W(global, N=200), 8-col x 3-row tile ----------
// ct in 0..24 (cols 8ct..8ct+7), rt in 0..9 (rows 3rt..3rt+2).
// X AND W double-buffered in registers: loads for kt+1 issued a full
// iteration (~380 cyc) before use -> covers ~120-cyc LDS latency.
template<int K>
__device__ inline void gemm_w8(const float* Xl, int xstr, const float* __restrict__ W,
                               int ct, int rt, float acc[3][8]) {
    const float* wp = W + 8 * ct;
    float4 wa[4], wb[4], xc[3];
#pragma unroll
    for (int u = 0; u < 4; u++) {
        wa[u] = *(const float4*)(wp + u * 200);
        wb[u] = *(const float4*)(wp + u * 200 + 4);
    }
#pragma unroll
    for (int m = 0; m < 3; m++) xc[m] = *(const float4*)(Xl + (rt * 3 + m) * xstr);
#pragma unroll 1
    for (int kt = 0; kt < K / 4 - 1; kt++) {
        float4 na[4], nb[4], nx[3];
#pragma unroll
        for (int u = 0; u < 4; u++) {
            na[u] = *(const float4*)(wp + (kt * 4 + 4 + u) * 200);
            nb[u] = *(const float4*)(wp + (kt * 4 + 4 + u) * 200 + 4);
        }
#pragma unroll
        for (int m = 0; m < 3; m++)
            nx[m] = *(const float4*)(Xl + (rt * 3 + m) * xstr + kt * 4 + 4);
#pragma unroll
        for (int m = 0; m < 3; m++) {
            float* lo = acc[m]; float* hi = acc[m] + 4;
            FMA4(xc[m].x, wa[0], lo); FMA4(xc[m].x, wb[0], hi);
            FMA4(xc[m].y, wa[1], lo); FMA4(xc[m].y, wb[1], hi);
            FMA4(xc[m].z, wa[2], lo); FMA4(xc[m].z, wb[2], hi);
            FMA4(xc[m].w, wa[3], lo); FMA4(xc[m].w, wb[3], hi);
        }
#pragma unroll
        for (int u = 0; u < 4; u++) { wa[u] = na[u]; wb[u] = nb[u]; }
#pragma unroll
        for (int m = 0; m < 3; m++) xc[m] = nx[m];
    }
#pragma unroll
    for (int m = 0; m < 3; m++) {
        float* lo = acc[m]; float* hi = acc[m] + 4;
        FMA4(xc[m].x, wa[0], lo); FMA4(xc[m].x, wb[0], hi);
        FMA4(xc[m].y, wa[1], lo); FMA4(xc[m].y, wb[1], hi);
        FMA4(xc[m].z, wa[2], lo); FMA4(xc[m].z, wb[2], hi);
        FMA4(xc[m].w, wa[3], lo); FMA4(xc[m].w, wb[3], hi);
    }
}

// ---------- gemm_w8d: dual-sample version (shared W stream) ----------
template<int K>
__device__ inline void gemm_w8d(const float* X0, const float* X1, int xstr,
                                const float* __restrict__ W,
                                int ct, int rt, float acc0[3][8], float acc1[3][8]) {
    const float* wp = W + 8 * ct;
    float4 wa[4], wb[4], x0[3], x1[3];
#pragma unroll
    for (int u = 0; u < 4; u++) {
        wa[u] = *(const float4*)(wp + u * 200);
        wb[u] = *(const float4*)(wp + u * 200 + 4);
    }
#pragma unroll
    for (int m = 0; m < 3; m++) {
        x0[m] = *(const float4*)(X0 + (rt * 3 + m) * xstr);
        x1[m] = *(const float4*)(X1 + (rt * 3 + m) * xstr);
    }
#pragma unroll 1
    for (int kt = 0; kt < K / 4 - 1; kt++) {
        float4 na[4], nb[4], n0[3], n1[3];
#pragma unroll
        for (int u = 0; u < 4; u++) {
            na[u] = *(const float4*)(wp + (kt * 4 + 4 + u) * 200);
            nb[u] = *(const float4*)(wp + (kt * 4 + 4 + u) * 200 + 4);
        }
#pragma unroll
        for (int m = 0; m < 3; m++) {
            n0[m] = *(const float4*)(X0 + (rt * 3 + m) * xstr + kt * 4 + 4);
            n1[m] = *(const float4*)(X1 + (rt * 3 + m) * xstr + kt * 4 + 4);
        }
#pragma unroll
        for (int m = 0; m < 3; m++) {
            float* lo = acc0[m]; float* hi = acc0[m] + 4;
            FMA4(x0[m].x, wa[0], lo); FMA4(x0[m].x, wb[0], hi);
            FMA4(x0[m].y, wa[1], lo); FMA4(x0[m].y, wb[1], hi);
            FMA4(x0[m].z, wa[2], lo); FMA4(x0[m].z, wb[2], hi);
            FMA4(x0[m].w, wa[3], lo); FMA4(x0[m].w, wb[3], hi);
        }
#pragma unroll
        for (int m = 0; m < 3; m++) {
            float* lo = acc1[m]; float* hi = acc1[m] + 4;
            FMA4(x1[m].x, wa[0], lo); FMA4(x1[m].x, wb[0], hi);
            FMA4(x1[m].y, wa[1], lo); FMA4(x1[m].y, wb[1], hi);
            FMA4(x1[m].z, wa[2], lo); FMA4(x1[m].z, wb[2], hi);
            FMA4(x1[m].w, wa[3], lo); FMA4(x1[m].w, wb[3], hi);
        }
#pragma unroll
        for (int u = 0; u < 4; u++) { wa[u] = na[u]; wb[u] = nb[u]; }
#pragma unroll
        for (int m = 0; m < 3; m++) { x0[m] = n0[m]; x1[m] = n1[m]; }
    }
#pragma unroll
    for (int m = 0; m < 3; m++) {
        float* lo = acc0[m]; float* hi = acc0[m] + 4;
        FMA4(x0[m].x, wa[0], lo); FMA4(x0[m].x, wb[0], hi);
        FMA4(x0[m].y, wa[1], lo); FMA4(x0[m].y, wb[1], hi);
        FMA4(x0[m].z, wa[2], lo); FMA4(x0[m].z, wb[2], hi);
        FMA4(x0[m].w, wa[3], lo); FMA4(x0[m].w, wb[3], hi);
    }
#pragma unroll
    for (int m = 0; m < 3; m++) {
        float* lo = acc1[m]; float* hi = acc1[m] + 4;
        FMA4(x1[m].x, wa[0], lo); FMA4(x1[m].x, wb[0], hi);
        FMA4(x1[m].y, wa[1], lo); FMA4(x1[m].y, wb[1], hi);
        FMA4(x1[m].z, wa[2], lo); FMA4(x1[m].z, wb[2], hi);
        FMA4(x1[m].w, wa[3], lo); FMA4(x1[m].w, wb[3], hi);
    }
}

// ---------- gemm_w4_pf: X(LDS) @ W(global), depth-8 register pipeline ----------
template<int RPT, int N, int K>
__device__ inline void gemm_w4_pf(const float* Xl, int xstr, const float* __restrict__ W,
                                  int ct, int rt, float acc[][4]) {
    const float* wp = W + 4 * ct;
    float4 wreg[8];
#pragma unroll
    for (int u = 0; u < 8; u++) wreg[u] = *(const float4*)(wp + u * N);
#pragma unroll 1
    for (int kt = 0; kt < K / 8 - 1; kt++) {
        float4 wnxt[8];
#pragma unroll
        for (int u = 0; u < 8; u++) wnxt[u] = *(const float4*)(wp + (kt * 8 + 8 + u) * N);
#pragma unroll
        for (int m = 0; m < RPT; m++) {
            const float* xr = Xl + (rt * RPT + m) * xstr + kt * 8;
            float4 a0 = *(const float4*)(xr);
            float4 a1 = *(const float4*)(xr + 4);
            fma_tile8(a0, a1, wreg, acc[m]);
        }
#pragma unroll
        for (int u = 0; u < 8; u++) wreg[u] = wnxt[u];
    }
    {
        const int kb = K - 8;
#pragma unroll
        for (int m = 0; m < RPT; m++) {
            const float* xr = Xl + (rt * RPT + m) * xstr + kb;
            float4 a0 = *(const float4*)(xr);
            float4 a1 = *(const float4*)(xr + 4);
            fma_tile8(a0, a1, wreg, acc[m]);
        }
    }
}

// ---------- gemm_w4_pf_dual ----------
template<int RPT, int N, int K>
__device__ inline void gemm_w4_pf_dual(const float* X0, const float* X1, int xstr,
                                       const float* __restrict__ W,
                                       int ct, int rt,
                                       float acc0[][4], float acc1[][4]) {
    const float* wp = W + 4 * ct;
    float4 wreg[8];
#pragma unroll
    for (int u = 0; u < 8; u++) wreg[u] = *(const float4*)(wp + u * N);
#pragma unroll 1
    for (int kt = 0; kt < K / 8 - 1; kt++) {
        float4 wnxt[8];
#pragma unroll
        for (int u = 0; u < 8; u++) wnxt[u] = *(const float4*)(wp + (kt * 8 + 8 + u) * N);
#pragma unroll
        for (int m = 0; m < RPT; m++) {
            const float* xr = X0 + (rt * RPT + m) * xstr + kt * 8;
            float4 a0 = *(const float4*)(xr);
            float4 a1 = *(const float4*)(xr + 4);
            fma_tile8(a0, a1, wreg, acc0[m]);
        }
#pragma unroll
        for (int m = 0; m < RPT; m++) {
            const float* xr = X1 + (rt * RPT + m) * xstr + kt * 8;
            float4 a0 = *(const float4*)(xr);
            float4 a1 = *(const float4*)(xr + 4);
            fma_tile8(a0, a1, wreg, acc1[m]);
        }
#pragma unroll
        for (int u = 0; u < 8; u++) wreg[u] = wnxt[u];
    }
    {
        const int kb = K - 8;
#pragma unroll
        for (int m = 0; m < RPT; m++) {
            const float* xr = X0 + (rt * RPT + m) * xstr + kb;
            float4 a0 = *(const float4*)(xr);
            float4 a1 = *(const float4*)(xr + 4);
            fma_tile8(a0, a1, wreg, acc0[m]);
        }
#pragma unroll
        for (int m = 0; m < RPT; m++) {
            const float* xr = X1 + (rt * RPT + m) * xstr + kb;
            float4 a0 = *(const float4*)(xr);
            float4 a1 = *(const float4*)(xr + 4);
            fma_tile8(a0, a1, wreg, acc1[m]);
        }
    }
}

// ---------- gemm_a32: Al(LDS, stride 32) @ Xl(LDS) ----------
template<int RPT>
__device__ inline void gemm_a32(const float* Al, const float* Xl, int xstr,
                                int ct, int rt, float acc[][4]) {
#pragma unroll
    for (int k4 = 0; k4 < 8; k4++) {
        float4 xv0 = *(const float4*)(Xl + (4 * k4 + 0) * xstr + 4 * ct);
        float4 xv1 = *(const float4*)(Xl + (4 * k4 + 1) * xstr + 4 * ct);
        float4 xv2 = *(const float4*)(Xl + (4 * k4 + 2) * xstr + 4 * ct);
        float4 xv3 = *(const float4*)(Xl + (4 * k4 + 3) * xstr + 4 * ct);
#pragma unroll
        for (int m = 0; m < RPT; m++) {
            float4 av = *(const float4*)(Al + (rt * RPT + m) * 32 + 4 * k4);
            FMA4(av.x, xv0, acc[m]);
            FMA4(av.y, xv1, acc[m]);
            FMA4(av.z, xv2, acc[m]);
            FMA4(av.w, xv3, acc[m]);
        }
    }
}

// ---------- gemm_a32_dual ----------
template<int RPT>
__device__ inline void gemm_a32_dual(const float* Al0, const float* X0,
                                     const float* Al1, const float* X1,
                                     int xstr, int ct, int rt,
                                     float acc0[][4], float acc1[][4]) {
#pragma unroll
    for (int k4 = 0; k4 < 8; k4++) {
        float4 x00 = *(const float4*)(X0 + (4 * k4 + 0) * xstr + 4 * ct);
        float4 x01 = *(const float4*)(X0 + (4 * k4 + 1) * xstr + 4 * ct);
        float4 x02 = *(const float4*)(X0 + (4 * k4 + 2) * xstr + 4 * ct);
        float4 x03 = *(const float4*)(X0 + (4 * k4 + 3) * xstr + 4 * ct);
        float4 x10 = *(const float4*)(X1 + (4 * k4 + 0) * xstr + 4 * ct);
        float4 x11 = *(const float4*)(X1 + (4 * k4 + 1) * xstr + 4 * ct);
        float4 x12 = *(const float4*)(X1 + (4 * k4 + 2) * xstr + 4 * ct);
        float4 x13 = *(const float4*)(X1 + (4 * k4 + 3) * xstr + 4 * ct);
#pragma unroll
        for (int m = 0; m < RPT; m++) {
            float4 av0 = *(const float4*)(Al0 + (rt * RPT + m) * 32 + 4 * k4);
            FMA4(av0.x, x00, acc0[m]);
            FMA4(av0.y, x01, acc0[m]);
            FMA4(av0.z, x02, acc0[m]);
            FMA4(av0.w, x03, acc0[m]);
            float4 av1 = *(const float4*)(Al1 + (rt * RPT + m) * 32 + 4 * k4);
            FMA4(av1.x, x10, acc1[m]);
            FMA4(av1.y, x11, acc1[m]);
            FMA4(av1.z, x12, acc1[m]);
            FMA4(av1.w, x13, acc1[m]);
        }
    }
}

// ---------- gemm_w150_pf: N=150, float2-pair columns ----------
__device__ inline void gemm_w150_pf(const float* Xl, const float* __restrict__ W,
                                    int ct2, int rt2, float acc[5][4], int off23) {
    const float* wp = W + 4 * ct2;
    float2 wa[8], wb[8];
#pragma unroll
    for (int u = 0; u < 8; u++) {
        wa[u] = *(const float2*)(wp + u * 150);
        wb[u] = *(const float2*)(wp + u * 150 + off23);
    }
#pragma unroll 1
    for (int kt = 0; kt < 24; kt++) {
        float2 na[8], nb[8];
#pragma unroll
        for (int u = 0; u < 8; u++) {
            int k = kt * 8 + 8 + u;
            na[u] = *(const float2*)(wp + k * 150);
            nb[u] = *(const float2*)(wp + k * 150 + off23);
        }
#pragma unroll
        for (int m = 0; m < 5; m++) {
            const float* xr = Xl + (rt2 * 5 + m) * FD + kt * 8;
            float4 a0 = *(const float4*)(xr);
            float4 a1 = *(const float4*)(xr + 4);
            float av[8] = {a0.x, a0.y, a0.z, a0.w, a1.x, a1.y, a1.z, a1.w};
#pragma unroll
            for (int u = 0; u < 8; u++) {
                acc[m][0] = fmaf(av[u], wa[u].x, acc[m][0]);
                acc[m][1] = fmaf(av[u], wa[u].y, acc[m][1]);
                acc[m][2] = fmaf(av[u], wb[u].x, acc[m][2]);
                acc[m][3] = fmaf(av[u], wb[u].y, acc[m][3]);
            }
        }
#pragma unroll
        for (int u = 0; u < 8; u++) { wa[u] = na[u]; wb[u] = nb[u]; }
    }
#pragma unroll
    for (int m = 0; m < 5; m++) {
        const float* xr = Xl + (rt2 * 5 + m) * FD + 192;
        float4 a0 = *(const float4*)(xr);
        float4 a1 = *(const float4*)(xr + 4);
        float av[8] = {a0.x, a0.y, a0.z, a0.w, a1.x, a1.y, a1.z, a1.w};
#pragma unroll
        for (int u = 0; u < 8; u++) {
            acc[m][0] = fmaf(av[u], wa[u].x, acc[m][0]);
            acc[m][1] = fmaf(av[u], wa[u].y, acc[m][1]);
            acc[m][2] = fmaf(av[u], wb[u].x, acc[m][2]);
            acc[m][3] = fmaf(av[u], wb[u].y, acc[m][3]);
        }
    }
}

// ================= K2: conv2 fused + F2 = relu(h2 @ Wt + bt) =================
__global__ __launch_bounds__(256) void k_f2(
    const float* __restrict__ C1,
    const float* __restrict__ Wc2, const float* __restrict__ bc2,
    const float* __restrict__ Wt, const float* __restrict__ bt,
    float* __restrict__ F2) {
    const int b = blockIdx.x, t = threadIdx.x;
    __shared__ float buf[S * 130];
    __shared__ float w2l[90 * 32];
    const int c8 = t % 25, r8 = t / 25;     // w8 GEMM map (t<250)
    const int c3p = t & 63, sg = t >> 6;
    const int p0 = 2 * c3p;

    for (int idx = t; idx < 2700; idx += 256) {
        int ch = idx / 90, r = idx % 90;
        w2l[r * 32 + ch] = Wc2[idx];
    }
    for (int idx = t; idx < 180; idx += 256) {
        int r = idx >> 1, z = idx & 1;
        w2l[r * 32 + 30 + z] = 0.f;
    }
    float bias[8];
#pragma unroll
    for (int m = 0; m < 8; m++) {
        int ch = sg * 8 + m;
        bias[m] = bc2[ch < S ? ch : 0];
    }
    float acc[3][8];
    zacc8(acc);

    for (int ks = 0; ks < 8; ks++) {
        for (int idx = t; idx < S * 32; idx += 256) {
            int s = idx >> 5, u = idx & 31;
            float4 v = *(const float4*)(C1 + (size_t)(b * S + s) * TT + ks * 128 + 4 * u);
            float* d = buf + s * 130 + 1 + 4 * u;
            d[0] = v.x; d[1] = v.y; d[2] = v.z; d[3] = v.w;
        }
        if (t < 60) {
            int s = t % S;
            if (t < S) {
                int gt = ks * 128 - 1;
                buf[s * 130] = (gt >= 0) ? C1[(size_t)(b * S + s) * TT + gt] : 0.f;
            } else {
                int gt = ks * 128 + 128;
                buf[s * 130 + 129] = (gt < TT) ? C1[(size_t)(b * S + s) * TT + gt] : 0.f;
            }
        }
        __syncthreads();
        // conv2 + relu into regs, with next-si prefetch of data AND weights
        float a0[8], a1[8];
#pragma unroll
        for (int m = 0; m < 8; m++) { a0[m] = bias[m]; a1[m] = bias[m]; }
        float2 va = *(const float2*)(buf + p0);
        float2 vb = *(const float2*)(buf + p0 + 2);
        float4 wv0a = *(const float4*)(w2l + sg * 8);
        float4 wv0b = *(const float4*)(w2l + sg * 8 + 4);
        float4 wv1a = *(const float4*)(w2l + sg * 8 + 32);
        float4 wv1b = *(const float4*)(w2l + sg * 8 + 36);
        float4 wv2a = *(const float4*)(w2l + sg * 8 + 64);
        float4 wv2b = *(const float4*)(w2l + sg * 8 + 68);
        for (int si = 0; si < S; si++) {
            int sn = (si + 1 < S) ? si + 1 : 0;
            float2 nva = *(const float2*)(buf + sn * 130 + p0);
            float2 nvb = *(const float2*)(buf + sn * 130 + p0 + 2);
            const float* wr2 = w2l + sn * 96 + sg * 8;
            float4 nw0a = *(const float4*)(wr2);
            float4 nw0b = *(const float4*)(wr2 + 4);
            float4 nw1a = *(const float4*)(wr2 + 32);
            float4 nw1b = *(const float4*)(wr2 + 36);
            float4 nw2a = *(const float4*)(wr2 + 64);
            float4 nw2b = *(const float4*)(wr2 + 68);
            float w0[8] = {wv0a.x, wv0a.y, wv0a.z, wv0a.w, wv0b.x, wv0b.y, wv0b.z, wv0b.w};
            float w1[8] = {wv1a.x, wv1a.y, wv1a.z, wv1a.w, wv1b.x, wv1b.y, wv1b.z, wv1b.w};
            float w2[8] = {wv2a.x, wv2a.y, wv2a.z, wv2a.w, wv2b.x, wv2b.y, wv2b.z, wv2b.w};
#pragma unroll
            for (int m = 0; m < 8; m++) {
                a0[m] = fmaf(w0[m], va.x, fmaf(w1[m], va.y, fmaf(w2[m], vb.x, a0[m])));
                a1[m] = fmaf(w0[m], va.y, fmaf(w1[m], vb.x, fmaf(w2[m], vb.y, a1[m])));
            }
            va = nva; vb = nvb;
            wv0a = nw0a; wv0b = nw0b; wv1a = nw1a; wv1b = nw1b; wv2a = nw2a; wv2b = nw2b;
        }
        __syncthreads();
#pragma unroll
        for (int m = 0; m < 8; m++) {
            int ch = sg * 8 + m;
            if (ch < S) {
                float2 o = {fmaxf(a0[m], 0.f), fmaxf(a1[m], 0.f)};
                *(float2*)(buf + ch * 128 + p0) = o;
            }
        }
        __syncthreads();
        if (t < 250)
            gemm_w8<128>(buf, 128, Wt + (size_t)ks * 128 * FD, c8, r8, acc);
        __syncthreads();
    }
    if (t < 250) {
        float4 b0 = *(const float4*)(bt + 8 * c8);
        float4 b1 = *(const float4*)(bt + 8 * c8 + 4);
#pragma unroll
        for (int m = 0; m < 3; m++) {
            int row = r8 * 3 + m;
            float4 o0, o1;
            o0.x = fmaxf(acc[m][0] + b0.x, 0.f);
            o0.y = fmaxf(acc[m][1] + b0.y, 0.f);
            o0.z = fmaxf(acc[m][2] + b0.z, 0.f);
            o0.w = fmaxf(acc[m][3] + b0.w, 0.f);
            o1.x = fmaxf(acc[m][4] + b1.x, 0.f);
            o1.y = fmaxf(acc[m][5] + b1.y, 0.f);
            o1.z = fmaxf(acc[m][6] + b1.z, 0.f);
            o1.w = fmaxf(acc[m][7] + b1.w, 0.f);
            *(float4*)(F2 + (size_t)(b * S + row) * FD + 8 * c8) = o0;
            *(float4*)(F2 + (size_t)(b * S + row) * FD + 8 * c8 + 4) = o1;
        }
    }
}

// ================= K3: k_att = AF + Gv(loc|glb) =================
__global__ __launch_bounds__(256) void k_att(
    const float* __restrict__ F2, const float* __restrict__ Wa,
    const float* __restrict__ adj, const float* __restrict__ Wl,
    const float* __restrict__ Wgl,
    float* __restrict__ AF, float* __restrict__ Gv) {
    const int b = blockIdx.x, t = threadIdx.x;
    __shared__ float A[32 * FD];
    __shared__ float Bu[32 * FD];
    __shared__ float scl[32 * 32];
    __shared__ float adjl[32 * 32];
    for (int idx = t; idx < 32 * FD; idx += 256) {
        A[idx] = (idx < S * FD) ? F2[(size_t)b * S * FD + idx] : 0.f;
        if (idx >= S * FD) Bu[idx] = 0.f;
    }
    for (int idx = t; idx < 1024; idx += 256) {
        int r = idx >> 5, cc = idx & 31;
        adjl[idx] = (r < S && cc < S) ? adj[r * S + cc] : 0.f;
        scl[idx] = 0.f;
    }
    __syncthreads();
    const int ct = t % 50, rt = t / 50;
    const int c8 = t % 25, r8 = t / 25;
    // P = F2 @ Wa -> Bu  (w8)
    if (t < 250) {
        float g[3][8];
        zacc8(g);
        gemm_w8<FD>(A, FD, Wa, c8, r8, g);
#pragma unroll
        for (int m = 0; m < 3; m++) {
            float4 o0 = {g[m][0], g[m][1], g[m][2], g[m][3]};
            float4 o1 = {g[m][4], g[m][5], g[m][6], g[m][7]};
            *(float4*)(Bu + (r8 * 3 + m) * FD + 8 * c8) = o0;
            *(float4*)(Bu + (r8 * 3 + m) * FD + 8 * c8 + 4) = o1;
        }
    }
    __syncthreads();
    // scl[i,j] = relu(P[i,:] . F2[j,:])
    for (int idx = t; idx < S * S; idx += 256) {
        int i = idx / S, j = idx % S;
        float a = 0.f;
        for (int f4 = 0; f4 < 50; f4++) {
            float4 p = *(const float4*)(Bu + i * FD + 4 * f4);
            float4 q = *(const float4*)(A + j * FD + 4 * f4);
            a = fmaf(p.x, q.x, a); a = fmaf(p.y, q.y, a);
            a = fmaf(p.z, q.z, a); a = fmaf(p.w, q.w, a);
        }
        scl[i * 32 + j] = fmaxf(a, 0.f);
    }
    __syncthreads();
    if (t < S) {
        float mx = -1e30f;
        for (int j = 0; j < S; j++) mx = fmaxf(mx, scl[t * 32 + j]);
        float den = 0.f;
        for (int j = 0; j < S; j++) den += expf(scl[t * 32 + j] - mx);
        float inv = 1.f / den;
        for (int j = 0; j < S; j++) scl[t * 32 + j] = expf(scl[t * 32 + j] - mx) * inv;
    }
    __syncthreads();
    for (int idx = t; idx < S * S; idx += 256)
        AF[(size_t)b * S * S + idx] = scl[(idx / S) * 32 + (idx % S)];
    // loc: T = adj@F2 -> Bu ; Gv[:, :150] = relu(T @ Wl)
    {
        float acc[6][4];
        zacc<6>(acc);
        if (t < 250) gemm_a32<6>(adjl, A, FD, ct, rt, acc);
        __syncthreads();
        if (t < 250)
#pragma unroll
            for (int m = 0; m < 6; m++) {
                float4 o = {acc[m][0], acc[m][1], acc[m][2], acc[m][3]};
                *(float4*)(Bu + (rt * 6 + m) * FD + 4 * ct) = o;
            }
        __syncthreads();
    }
    const int ct2 = t % 38, rt2 = t / 38;
    const bool full = (4 * ct2 + 2) < 150;
    const int off23 = full ? 2 : -2;
    if (t < 228) {
        float a2[5][4];
        zacc<5>(a2);
        gemm_w150_pf(Bu, Wl, ct2, rt2, a2, off23);
#pragma unroll
        for (int m = 0; m < 5; m++) {
            float* o = Gv + (size_t)(b * S + rt2 * 5 + m) * 300 + 4 * ct2;
            o[0] = fmaxf(a2[m][0], 0.f); o[1] = fmaxf(a2[m][1], 0.f);
            if (full) { o[2] = fmaxf(a2[m][2], 0.f); o[3] = fmaxf(a2[m][3], 0.f); }
        }
    }
    __syncthreads();
    // glb: T = AF@F2 -> Bu ; Gv[:, 150:] = relu(T @ Wgl)
    {
        float acc[6][4];
        zacc<6>(acc);
        if (t < 250) gemm_a32<6>(scl, A, FD, ct, rt, acc);
        __syncthreads();
        if (t < 250)
#pragma unroll
            for (int m = 0; m < 6; m++) {
                float4 o = {acc[m][0], acc[m][1], acc[m][2], acc[m][3]};
                *(float4*)(Bu + (rt * 6 + m) * FD + 4 * ct) = o;
            }
        __syncthreads();
    }
    if (t < 228) {
        float a2[5][4];
        zacc<5>(a2);
        gemm_w150_pf(Bu, Wgl, ct2, rt2, a2, off23);
#pragma unroll
        for (int m = 0; m < 5; m++) {
            float* o = Gv + (size_t)(b * S + rt2 * 5 + m) * 300 + 150 + 4 * ct2;
            o[0] = fmaxf(a2[m][0], 0.f); o[1] = fmaxf(a2[m][1], 0.f);
            if (full) { o[2] = fmaxf(a2[m][2], 0.f); o[3] = fmaxf(a2[m][3], 0.f); }
        }
    }
}

// ================= K4: k_mgcn — dual-sample, w8 GEMM core =================
__global__ __launch_bounds__(256, 2) void k_mgcn(
    const float* __restrict__ F2g, const float* __restrict__ AFg,
    const float* __restrict__ adj,
    const float* __restrict__ Wg1, const float* __restrict__ Wg2,
    const float* __restrict__ Wm1, const float* __restrict__ Wm2,
    const float* __restrict__ Wm3, const float* __restrict__ wg,
    const float* __restrict__ Wp1, const float* __restrict__ Wp2,
    const float* __restrict__ Wp3,
    float* __restrict__ Rws, float* __restrict__ Gh) {
    const int b0 = blockIdx.x * 2, b1 = b0 + 1;
    const int t = threadIdx.x;
    __shared__ float A0[32 * FD], A1[32 * FD];
    __shared__ float afl0[1024], afl1[1024];
    __shared__ float adjl[1024];
    __shared__ float sk[192];
    __shared__ float gl[192];
    const int ct = t % 50, rt = t / 50;     // a32 map
    const int c8 = t % 25, r8 = t / 25;     // w8 / Wp / G_k map

    for (int idx = t; idx < 1500; idx += 256) {
        *(float4*)(A0 + 4 * idx) = *(const float4*)(F2g + (size_t)b0 * S * FD + 4 * idx);
        *(float4*)(A1 + 4 * idx) = *(const float4*)(F2g + (size_t)b1 * S * FD + 4 * idx);
    }
    for (int idx = t; idx < 400; idx += 256) { A0[6000 + idx] = 0.f; A1[6000 + idx] = 0.f; }
    for (int idx = t; idx < 1024; idx += 256) {
        int r = idx >> 5, cc = idx & 31;
        bool in = (r < S && cc < S);
        afl0[idx] = in ? AFg[(size_t)b0 * S * S + r * S + cc] : 0.f;
        afl1[idx] = in ? AFg[(size_t)b1 * S * S + r * S + cc] : 0.f;
        adjl[idx] = in ? adj[r * S + cc] : 0.f;
    }
    if (t < 192) sk[t] = 0.f;
    __syncthreads();

#define DW6(AC0, AC1, RELU)                                                 \
    if (t < 250) {                                                          \
        _Pragma("unroll")                                                   \
        for (int m = 0; m < 6; m++) {                                       \
            float4 o0, o1;                                                  \
            o0.x = RELU ? fmaxf(AC0[m][0], 0.f) : AC0[m][0];                \
            o0.y = RELU ? fmaxf(AC0[m][1], 0.f) : AC0[m][1];                \
            o0.z = RELU ? fmaxf(AC0[m][2], 0.f) : AC0[m][2];                \
            o0.w = RELU ? fmaxf(AC0[m][3], 0.f) : AC0[m][3];                \
            o1.x = RELU ? fmaxf(AC1[m][0], 0.f) : AC1[m][0];                \
            o1.y = RELU ? fmaxf(AC1[m][1], 0.f) : AC1[m][1];                \
            o1.z = RELU ? fmaxf(AC1[m][2], 0.f) : AC1[m][2];                \
            o1.w = RELU ? fmaxf(AC1[m][3], 0.f) : AC1[m][3];                \
            *(float4*)(A0 + (rt * 6 + m) * FD + 4 * ct) = o0;               \
            *(float4*)(A1 + (rt * 6 + m) * FD + 4 * ct) = o1;               \
        }                                                                   \
    }

#define DW8(G0, G1, RELU)                                                   \
    if (t < 250) {                                                          \
        _Pragma("unroll")                                                   \
        for (int m = 0; m < 3; m++) {                                       \
            int row = r8 * 3 + m;                                           \
            float4 o0, o1, p0v, p1v;                                        \
            o0.x = RELU ? fmaxf(G0[m][0], 0.f) : G0[m][0];                  \
            o0.y = RELU ? fmaxf(G0[m][1], 0.f) : G0[m][1];                  \
            o0.z = RELU ? fmaxf(G0[m][2], 0.f) : G0[m][2];                  \
            o0.w = RELU ? fmaxf(G0[m][3], 0.f) : G0[m][3];                  \
            p0v.x = RELU ? fmaxf(G0[m][4], 0.f) : G0[m][4];                 \
            p0v.y = RELU ? fmaxf(G0[m][5], 0.f) : G0[m][5];                 \
            p0v.z = RELU ? fmaxf(G0[m][6], 0.f) : G0[m][6];                 \
            p0v.w = RELU ? fmaxf(G0[m][7], 0.f) : G0[m][7];                 \
            o1.x = RELU ? fmaxf(G1[m][0], 0.f) : G1[m][0];                  \
            o1.y = RELU ? fmaxf(G1[m][1], 0.f) : G1[m][1];                  \
            o1.z = RELU ? fmaxf(G1[m][2], 0.f) : G1[m][2];                  \
            o1.w = RELU ? fmaxf(G1[m][3], 0.f) : G1[m][3];                  \
            p1v.x = RELU ? fmaxf(G1[m][4], 0.f) : G1[m][4];                 \
            p1v.y = RELU ? fmaxf(G1[m][5], 0.f) : G1[m][5];                 \
            p1v.z = RELU ? fmaxf(G1[m][6], 0.f) : G1[m][6];                 \
            p1v.w = RELU ? fmaxf(G1[m][7], 0.f) : G1[m][7];                 \
            *(float4*)(A0 + row * FD + 8 * c8) = o0;                        \
            *(float4*)(A0 + row * FD + 8 * c8 + 4) = p0v;                   \
            *(float4*)(A1 + row * FD + 8 * c8) = o1;                        \
            *(float4*)(A1 + row * FD + 8 * c8 + 4) = p1v;                   \
        }                                                                   \
    }

    // ---- xs chain, in place (destroys F2 in A0/A1) ----
    {
        float a0[6][4], a1[6][4];
        zacc<6>(a0); zacc<6>(a1);
        if (t < 250) gemm_a32_dual<6>(adjl, A0, adjl, A1, FD, ct, rt, a0, a1);
        __syncthreads();
        DW6(a0, a1, false);
        __syncthreads();
    }
    {
        float g0[3][8], g1[3][8];
        zacc8(g0); zacc8(g1);
        if (t < 250) gemm_w8d<FD>(A0, A1, FD, Wg1, c8, r8, g0, g1);
        __syncthreads();
        DW8(g0, g1, true);
        __syncthreads();
    }
    {
        float a0[6][4], a1[6][4];
        zacc<6>(a0); zacc<6>(a1);
        if (t < 250) gemm_a32_dual<6>(adjl, A0, adjl, A1, FD, ct, rt, a0, a1);
        __syncthreads();
        DW6(a0, a1, false);
        __syncthreads();
    }
    float xsr0[3][8], xsr1[3][8];
    {
        float g0[3][8], g1[3][8];
        zacc8(g0); zacc8(g1);
        if (t < 250) gemm_w8d<FD>(A0, A1, FD, Wg2, c8, r8, g0, g1);
        __syncthreads();   // all reads of A=T2 done
#pragma unroll
        for (int m = 0; m < 3; m++)
#pragma unroll
            for (int j = 0; j < 8; j++) { xsr0[m][j] = g0[m][j]; xsr1[m][j] = g1[m][j]; }
        for (int idx = t; idx < 1500; idx += 256) {
            *(float4*)(A0 + 4 * idx) = *(const float4*)(F2g + (size_t)b0 * S * FD + 4 * idx);
            *(float4*)(A1 + 4 * idx) = *(const float4*)(F2g + (size_t)b1 * S * FD + 4 * idx);
        }
        __syncthreads();
    }

    // ---- MGCN chain: k = 0,1,2 ----
    const float* Wm[3] = {Wm1, Wm2, Wm3};
    const float* Wp[3] = {Wp1, Wp2, Wp3};
#pragma unroll 1
    for (int k = 0; k < 3; k++) {
        // T = AF @ X
        {
            float a0[6][4], a1[6][4];
            zacc<6>(a0); zacc<6>(a1);
            if (t < 250) gemm_a32_dual<6>(afl0, A0, afl1, A1, FD, ct, rt, a0, a1);
            __syncthreads();
            DW6(a0, a1, false);
            __syncthreads();
        }
        // X_k = relu(T @ Wm_k) in regs; H_k = 0.5*(X_k + xs) -> A; gate partials
        float g0[3][8], g1[3][8];
        zacc8(g0); zacc8(g1);
        if (t < 250) gemm_w8d<FD>(A0, A1, FD, Wm[k], c8, r8, g0, g1);
        __syncthreads();   // reads of A=T done
        if (t < 250) {
#pragma unroll
            for (int m = 0; m < 3; m++) {
                int row = r8 * 3 + m;
                float p0s = 0.f, p1s = 0.f;
                float h0[8], h1[8];
#pragma unroll
                for (int j = 0; j < 8; j++) {
                    float v0 = fmaxf(g0[m][j], 0.f);
                    float v1 = fmaxf(g1[m][j], 0.f);
                    g0[m][j] = v0; g1[m][j] = v1;      // keep relu'd X_k for restore
                    h0[j] = 0.5f * (v0 + xsr0[m][j]);
                    h1[j] = 0.5f * (v1 + xsr1[m][j]);
                    float wgv = wg[(8 * c8 + j) * 3 + k];
                    p0s = fmaf(h0[j], wgv, p0s);
                    p1s = fmaf(h1[j], wgv, p1s);
                }
                float4 oa = {h0[0], h0[1], h0[2], h0[3]};
                float4 ob = {h0[4], h0[5], h0[6], h0[7]};
                float4 oc = {h1[0], h1[1], h1[2], h1[3]};
                float4 od = {h1[4], h1[5], h1[6], h1[7]};
                *(float4*)(A0 + row * FD + 8 * c8) = oa;
                *(float4*)(A0 + row * FD + 8 * c8 + 4) = ob;
                *(float4*)(A1 + row * FD + 8 * c8) = oc;
                *(float4*)(A1 + row * FD + 8 * c8 + 4) = od;
                atomicAdd(&sk[row * 3 + k], p0s);
                atomicAdd(&sk[96 + row * 3 + k], p1s);
            }
        }
        __syncthreads();
        // R_k = H_k @ Wp_k -> workspace
        if (t < 250) {
            float a30[3][4], a31[3][4];
            zacc<3>(a30); zacc<3>(a31);
            gemm_w4_pf_dual<3, 100, FD>(A0, A1, FD, Wp[k], c8, r8, a30, a31);
#pragma unroll
            for (int m = 0; m < 3; m++) {
                float4 o0 = {a30[m][0], a30[m][1], a30[m][2], a30[m][3]};
                float4 o1 = {a31[m][0], a31[m][1], a31[m][2], a31[m][3]};
                *(float4*)(Rws + ((size_t)(k * BB + b0) * S + r8 * 3 + m) * 100 + 4 * c8) = o0;
                *(float4*)(Rws + ((size_t)(k * BB + b1) * S + r8 * 3 + m) * 100 + 4 * c8) = o1;
            }
        }
        __syncthreads();   // reads of A=H_k done
        if (k < 2) {
            DW8(g0, g1, false);   // g already relu'd: restore X_k
            __syncthreads();
        }
    }

    // ---- gates ----
    if (t < S) {
        float a0 = sk[t * 3 + 0], a1 = sk[t * 3 + 1], a2 = sk[t * 3 + 2];
        float m = fmaxf(a0, fmaxf(a1, a2));
        float e0 = expf(a0 - m), e1 = expf(a1 - m), e2 = expf(a2 - m);
        float inv = 1.f / (e0 + e1 + e2);
        gl[t * 3 + 0] = e0 * inv; gl[t * 3 + 1] = e1 * inv; gl[t * 3 + 2] = e2 * inv;
    } else if (t >= 64 && t < 64 + S) {
        int s = t - 64;
        float a0 = sk[96 + s * 3 + 0], a1 = sk[96 + s * 3 + 1], a2 = sk[96 + s * 3 + 2];
        float m = fmaxf(a0, fmaxf(a1, a2));
        float e0 = expf(a0 - m), e1 = expf(a1 - m), e2 = expf(a2 - m);
        float inv = 1.f / (e0 + e1 + e2);
        gl[96 + s * 3 + 0] = e0 * inv; gl[96 + s * 3 + 1] = e1 * inv; gl[96 + s * 3 + 2] = e2 * inv;
    }
    __syncthreads();

    // ---- G_k = adj @ diag(g_k) @ R_k ----
#pragma unroll 1
    for (int k = 0; k < 3; k++) {
        for (int idx = t; idx < S * 100; idx += 256) {
            int row = idx / 100, col = idx % 100;
            A0[row * FD + col] = Rws[((size_t)(k * BB + b0) * S) * 100 + idx];
            A1[row * FD + col] = Rws[((size_t)(k * BB + b1) * S) * 100 + idx];
        }
        for (int idx = t; idx < 1024; idx += 256) {
            int cc = idx & 31;
            afl0[idx] = (cc < S) ? adjl[idx] * gl[cc * 3 + k] : 0.f;
            afl1[idx] = (cc < S) ? adjl[idx] * gl[96 + cc * 3 + k] : 0.f;
        }
        __syncthreads();
        if (t < 250) {
            float a30[3][4], a31[3][4];
            zacc<3>(a30); zacc<3>(a31);
            gemm_a32_dual<3>(afl0, A0, afl1, A1, FD, c8, r8, a30, a31);
#pragma unroll
            for (int m = 0; m < 3; m++) {
                float4 o0 = {a30[m][0], a30[m][1], a30[m][2], a30[m][3]};
                float4 o1 = {a31[m][0], a31[m][1], a31[m][2], a31[m][3]};
                *(float4*)(Gh + (size_t)(b0 * S + r8 * 3 + m) * 300 + k * 100 + 4 * c8) = o0;
                *(float4*)(Gh + (size_t)(b1 * S + r8 * 3 + m) * 300 + k * 100 + 4 * c8) = o1;
            }
        }
        __syncthreads();
    }
#undef DW6
#undef DW8
}

// ================= K5: SE gates =================
__global__ __launch_bounds__(256) void k_se(const float* __restrict__ Gv, const float* __restrict__ Gh,
                                            const float* __restrict__ Ws1, const float* __restrict__ Ws2,
                                            const float* __restrict__ Wf1, const float* __restrict__ Wf2,
                                            float* __restrict__ wch, float* __restrict__ wft) {
    int b = blockIdx.x, t = threadIdx.x;
    __shared__ float mrow[S];
    __shared__ float u[15];
    __shared__ float mb[300];
    __shared__ float v[150];
    if (t < S) {
        float a = 0.f;
        const float* gp = Gv + ((size_t)b * S + t) * 300;
        for (int j = 0; j < 300; j++) a += gp[j];
        mrow[t] = a * (1.f / 300.f);
    }
    for (int j = t; j < 300; j += 256) {
        float a = 0.f;
        for (int s = 0; s < S; s++) a += Gh[(size_t)b * S * 300 + s * 300 + j];
        mb[j] = a * (1.f / S);
    }
    __syncthreads();
    if (t < 15) {
        float a = 0.f;
        for (int i = 0; i < S; i++) a += mrow[i] * Ws1[i * 15 + t];
        u[t] = fmaxf(a, 0.f);
    }
    if (t >= 64 && t < 64 + 150) {
        int h = t - 64;
        float a = 0.f;
        for (int j = 0; j < 300; j++) a += mb[j] * Wf1[j * 150 + h];
        v[h] = fmaxf(a, 0.f);
    }
    __syncthreads();
    if (t < S) {
        float a = 0.f;
        for (int h = 0; h < 15; h++) a += u[h] * Ws2[h * 30 + t];
        wch[b * S + t] = 1.f / (1.f + expf(-a));
    }
    for (int j = t; j < 300; j += 256) {
        float a = 0.f;
        for (int h = 0; h < 150; h++) a += v[h] * Wf2[h * 300 + j];
        wft[b * 300 + j] = 1.f / (1.f + expf(-a));
    }
}

// ================= K6: classifier + log_softmax =================
__global__ __launch_bounds__(256) void k_cls(const float* __restrict__ Gh, const float* __restrict__ Gv,
                                             const float* __restrict__ wch, const float* __restrict__ wft,
                                             const float* __restrict__ Wcls, const float* __restrict__ bcls,
                                             float* __restrict__ out) {
    const int b = blockIdx.x, t = threadIdx.x;
    __shared__ float red[NC][256];
    __shared__ float wftl[300];
    __shared__ float wchl[S];
    for (int j = t; j < 300; j += 256) wftl[j] = wft[(size_t)b * 300 + j];
    if (t < S) wchl[t] = wch[b * S + t];
    __syncthreads();
    float acc[NC];
#pragma unroll
    for (int c = 0; c < NC; c++) acc[c] = 0.f;
    for (int i = t; i < S * 600; i += 256) {
        int s = i / 600, j = i % 600;
        float gval = (j < 300)
            ? Gh[(size_t)b * S * 300 + s * 300 + j] * wchl[s]
            : Gv[(size_t)b * S * 300 + s * 300 + (j - 300)] * wftl[j - 300];
        const float* wr = Wcls + (size_t)i * NC;
#pragma unroll
        for (int c = 0; c < NC; c++) acc[c] = fmaf(gval, wr[c], acc[c]);
    }
#pragma unroll
    for (int c = 0; c < NC; c++) red[c][t] = acc[c];
    __syncthreads();
    for (int off = 128; off > 0; off >>= 1) {
        if (t < off) {
#pragma unroll
            for (int c = 0; c < NC; c++) red[c][t] += red[c][t + off];
        }
        __syncthreads();
    }
    if (t == 0) {
        float lg[NC];
        float mx = -1e30f;
#pragma unroll
        for (int c = 0; c < NC; c++) { lg[c] = red[c][0] + bcls[c]; mx = fmaxf(mx, lg[c]); }
        float den = 0.f;
#pragma unroll
        for (int c = 0; c < NC; c++) den += expf(lg[c] - mx);
        float lden = logf(den) + mx;
#pragma unroll
        for (int c = 0; c < NC; c++) out[b * NC + c] = lg[c] - lden;
    }
}

extern "C" void kernel_launch(void* const* d_in, const int* in_sizes, int n_in,
                              void* d_out, int out_size, void* d_ws, size_t ws_size,
                              hipStream_t stream) {
    const float* x    = (const float*)d_in[0];
    const float* adj  = (const float*)d_in[1];
    const float* Wc1  = (const float*)d_in[2];
    const float* bc1  = (const float*)d_in[3];
    const float* Wc2  = (const float*)d_in[4];
    const float* bc2  = (const float*)d_in[5];
    const float* Wt   = (const float*)d_in[6];
    const float* bt   = (const float*)d_in[7];
    const float* Wa   = (const float*)d_in[8];
    const float* Wm1  = (const float*)d_in[9];
    const float* Wm2  = (const float*)d_in[10];
    const float* Wm3  = (const float*)d_in[11];
    const float* Wg1  = (const float*)d_in[12];
    const float* Wg2  = (const float*)d_in[13];
    const float* wg   = (const float*)d_in[14];
    const float* Wp1  = (const float*)d_in[15];
    const float* Wp2  = (const float*)d_in[16];
    const float* Wp3  = (const float*)d_in[17];
    const float* Wl   = (const float*)d_in[18];
    const float* Wgl  = (const float*)d_in[19];
    const float* Ws1  = (const float*)d_in[20];
    const float* Ws2  = (const float*)d_in[21];
    const float* Wf1  = (const float*)d_in[22];
    const float* Wf2  = (const float*)d_in[23];
    const float* Wcls = (const float*)d_in[24];
    const float* bcls = (const float*)d_in[25];

    float* ws  = (float*)d_ws;
    float* C1  = ws + OFS_C1;
    float* F2  = ws + OFS_F2;
    float* AF  = ws + OFS_AF;
    float* GV  = ws + OFS_GV;
    float* GH  = ws + OFS_GH;
    float* WCH = ws + OFS_WCH;
    float* WFT = ws + OFS_WFT;
    float* RWS = ws + OFS_R;
    float* out = (float*)d_out;

    k_conv1<<<dim3(4, BB), 256, 0, stream>>>(x, Wc1, bc1, C1);
    k_f2<<<BB, 256, 0, stream>>>(C1, Wc2, bc2, Wt, bt, F2);
    k_att<<<BB, 256, 0, stream>>>(F2, Wa, adj, Wl, Wgl, AF, GV);
    k_mgcn<<<BB / 2, 256, 0, stream>>>(F2, AF, adj, Wg1, Wg2, Wm1, Wm2, Wm3, wg,
                                       Wp1, Wp2, Wp3, RWS, GH);
    k_se<<<BB, 256, 0, stream>>>(GV, GH, Ws1, Ws2, Wf1, Wf2, WCH, WFT);
    k_cls<<<BB, 256, 0, stream>>>(GH, GV, WCH, WFT, Wcls, bcls, out);
}

// Round 7
// 1146.926 us; speedup vs baseline: 1.1008x; 1.1008x over previous
//
#include <hip/hip_runtime.h>
#include <math.h>

#define S   30
#define FD  200
#define TT  1024
#define BB  1024
#define NC  7

// ---- workspace layout (float offsets), overlaid by live range ----
// C1 occupies [0, 31457280) and is LIVE until k_f2 completes.
// AF/GV/GH/RWS/WclsT overlay the C1 region and may only be written AFTER k_f2.
#define OFS_C1   0ull
#define OFS_F2   31457280ull
#define OFS_AF   0ull
#define OFS_GV   921600ull
#define OFS_GH   10137600ull
#define OFS_R    19691520ull     // 3*1024*30*100 floats
#define OFS_WT   28907520ull     // WclsT: 7*18000 = 126,000 floats

// ================= K1: conv1 + relu -> C1 =================
__global__ __launch_bounds__(256) void k_conv1(
    const float* __restrict__ x,
    const float* __restrict__ Wc1, const float* __restrict__ bc1,
    float* __restrict__ C1) {
    const int c = blockIdx.x, b = blockIdx.y;
    const int t = threadIdx.x;
    const int t0 = c * 256;
    __shared__ float xb[S * 258];
    __shared__ float w1l[90 * 32];
    for (int idx = t; idx < 2700; idx += 256) {
        int so = idx / 90, r = idx % 90;
        w1l[r * 32 + so] = Wc1[idx];
    }
    for (int idx = t; idx < 180; idx += 256) {
        int r = idx >> 1, z = idx & 1;
        w1l[r * 32 + 30 + z] = 0.f;
    }
    for (int idx = t; idx < S * 64; idx += 256) {
        int s = idx >> 6, u = idx & 63;
        float4 v = *(const float4*)(x + (size_t)(b * S + s) * TT + t0 + 4 * u);
        float* d = xb + s * 258 + 1 + 4 * u;
        d[0] = v.x; d[1] = v.y; d[2] = v.z; d[3] = v.w;
    }
    if (t < 60) {
        int s = t % S;
        if (t < S) {
            int gt = t0 - 1;
            xb[s * 258] = (gt >= 0) ? x[(size_t)(b * S + s) * TT + gt] : 0.f;
        } else {
            int gt = t0 + 256;
            xb[s * 258 + 257] = (gt < TT) ? x[(size_t)(b * S + s) * TT + gt] : 0.f;
        }
    }
    __syncthreads();
    float acc[32];
#pragma unroll
    for (int so = 0; so < 32; so++) acc[so] = (so < S) ? bc1[so] : 0.f;
    for (int si = 0; si < S; si++) {
        float v0 = xb[si * 258 + t];
        float v1 = xb[si * 258 + t + 1];
        float v2 = xb[si * 258 + t + 2];
        const float* wr = w1l + si * 96;
#pragma unroll
        for (int u = 0; u < 8; u++) {
            float4 w0 = *(const float4*)(wr + 4 * u);
            float4 w1 = *(const float4*)(wr + 32 + 4 * u);
            float4 w2 = *(const float4*)(wr + 64 + 4 * u);
            acc[4 * u + 0] = fmaf(w0.x, v0, fmaf(w1.x, v1, fmaf(w2.x, v2, acc[4 * u + 0])));
            acc[4 * u + 1] = fmaf(w0.y, v0, fmaf(w1.y, v1, fmaf(w2.y, v2, acc[4 * u + 1])));
            acc[4 * u + 2] = fmaf(w0.z, v0, fmaf(w1.z, v1, fmaf(w2.z, v2, acc[4 * u + 2])));
            acc[4 * u + 3] = fmaf(w0.w, v0, fmaf(w1.w, v1, fmaf(w2.w, v2, acc[4 * u + 3])));
        }
    }
#pragma unroll
    for (int so = 0; so < 32; so++) {
        if (so < S)
            C1[(size_t)(b * S + so) * TT + t0 + t] = fmaxf(acc[so], 0.f);
    }
}

// ---------- FMA tile helpers ----------
#define FMA4(av, wv, accm)                           \
    {                                                \
        accm[0] = fmaf(av, (wv).x, accm[0]);         \
        accm[1] = fmaf(av, (wv).y, accm[1]);         \
        accm[2] = fmaf(av, (wv).z, accm[2]);         \
        accm[3] = fmaf(av, (wv).w, accm[3]);         \
    }

__device__ inline void fma_tile8(const float4 a0, const float4 a1,
                                 const float4 w[8], float accm[4]) {
    FMA4(a0.x, w[0], accm); FMA4(a0.y, w[1], accm);
    FMA4(a0.z, w[2], accm); FMA4(a0.w, w[3], accm);
    FMA4(a1.x, w[4], accm); FMA4(a1.y, w[5], accm);
    FMA4(a1.z, w[6], accm); FMA4(a1.w, w[7], accm);
}

template<int RPT>
__device__ inline void zacc(float acc[][4]) {
#pragma unroll
    for (int m = 0; m < RPT; m++)
#pragma unroll
        for (int q = 0; q < 4; q++) acc[m][q] = 0.f;
}

// ---------- gemm_w4_pf: X(LDS) @ W(global), depth-8 register pipeline ----------
template<int RPT, int N, int K>
__device__ inline void gemm_w4_pf(const float* Xl, int xstr, const float* __restrict__ W,
                                  int ct, int rt, float acc[][4]) {
    const float* wp = W + 4 * ct;
    float4 wreg[8];
#pragma unroll
    for (int u = 0; u < 8; u++) wreg[u] = *(const float4*)(wp + u * N);
#pragma unroll 1
    for (int kt = 0; kt < K / 8 - 1; kt++) {
        float4 wnxt[8];
#pragma unroll
        for (int u = 0; u < 8; u++) wnxt[u] = *(const float4*)(wp + (kt * 8 + 8 + u) * N);
#pragma unroll
        for (int m = 0; m < RPT; m++) {
            const float* xr = Xl + (rt * RPT + m) * xstr + kt * 8;
            float4 a0 = *(const float4*)(xr);
            float4 a1 = *(const float4*)(xr + 4);
            fma_tile8(a0, a1, wreg, acc[m]);
        }
#pragma unroll
        for (int u = 0; u < 8; u++) wreg[u] = wnxt[u];
    }
    {
        const int kb = K - 8;
#pragma unroll
        for (int m = 0; m < RPT; m++) {
            const float* xr = Xl + (rt * RPT + m) * xstr + kb;
            float4 a0 = *(const float4*)(xr);
            float4 a1 = *(const float4*)(xr + 4);
            fma_tile8(a0, a1, wreg, acc[m]);
        }
    }
}

// ---------- gemm_w4_pf_dual: shared W stream, two X buffers / acc sets ----------
template<int RPT, int N, int K>
__device__ inline void gemm_w4_pf_dual(const float* X0, const float* X1, int xstr,
                                       const float* __restrict__ W,
                                       int ct, int rt,
                                       float acc0[][4], float acc1[][4]) {
    const float* wp = W + 4 * ct;
    float4 wreg[8];
#pragma unroll
    for (int u = 0; u < 8; u++) wreg[u] = *(const float4*)(wp + u * N);
#pragma unroll 1
    for (int kt = 0; kt < K / 8 - 1; kt++) {
        float4 wnxt[8];
#pragma unroll
        for (int u = 0; u < 8; u++) wnxt[u] = *(const float4*)(wp + (kt * 8 + 8 + u) * N);
#pragma unroll
        for (int m = 0; m < RPT; m++) {
            const float* xr = X0 + (rt * RPT + m) * xstr + kt * 8;
            float4 a0 = *(const float4*)(xr);
            float4 a1 = *(const float4*)(xr + 4);
            fma_tile8(a0, a1, wreg, acc0[m]);
        }
#pragma unroll
        for (int m = 0; m < RPT; m++) {
            const float* xr = X1 + (rt * RPT + m) * xstr + kt * 8;
            float4 a0 = *(const float4*)(xr);
            float4 a1 = *(const float4*)(xr + 4);
            fma_tile8(a0, a1, wreg, acc1[m]);
        }
#pragma unroll
        for (int u = 0; u < 8; u++) wreg[u] = wnxt[u];
    }
    {
        const int kb = K - 8;
#pragma unroll
        for (int m = 0; m < RPT; m++) {
            const float* xr = X0 + (rt * RPT + m) * xstr + kb;
            float4 a0 = *(const float4*)(xr);
            float4 a1 = *(const float4*)(xr + 4);
            fma_tile8(a0, a1, wreg, acc0[m]);
        }
#pragma unroll
        for (int m = 0; m < RPT; m++) {
            const float* xr = X1 + (rt * RPT + m) * xstr + kb;
            float4 a0 = *(const float4*)(xr);
            float4 a1 = *(const float4*)(xr + 4);
            fma_tile8(a0, a1, wreg, acc1[m]);
        }
    }
}

// ---------- gemm_a32: Al(LDS, stride 32) @ Xl(LDS) ----------
template<int RPT>
__device__ inline void gemm_a32(const float* Al, const float* Xl, int xstr,
                                int ct, int rt, float acc[][4]) {
#pragma unroll
    for (int k4 = 0; k4 < 8; k4++) {
        float4 xv0 = *(const float4*)(Xl + (4 * k4 + 0) * xstr + 4 * ct);
        float4 xv1 = *(const float4*)(Xl + (4 * k4 + 1) * xstr + 4 * ct);
        float4 xv2 = *(const float4*)(Xl + (4 * k4 + 2) * xstr + 4 * ct);
        float4 xv3 = *(const float4*)(Xl + (4 * k4 + 3) * xstr + 4 * ct);
#pragma unroll
        for (int m = 0; m < RPT; m++) {
            float4 av = *(const float4*)(Al + (rt * RPT + m) * 32 + 4 * k4);
            FMA4(av.x, xv0, acc[m]);
            FMA4(av.y, xv1, acc[m]);
            FMA4(av.z, xv2, acc[m]);
            FMA4(av.w, xv3, acc[m]);
        }
    }
}

// ---------- gemm_a32_dual ----------
template<int RPT>
__device__ inline void gemm_a32_dual(const float* Al0, const float* X0,
                                     const float* Al1, const float* X1,
                                     int xstr, int ct, int rt,
                                     float acc0[][4], float acc1[][4]) {
#pragma unroll
    for (int k4 = 0; k4 < 8; k4++) {
        float4 x00 = *(const float4*)(X0 + (4 * k4 + 0) * xstr + 4 * ct);
        float4 x01 = *(const float4*)(X0 + (4 * k4 + 1) * xstr + 4 * ct);
        float4 x02 = *(const float4*)(X0 + (4 * k4 + 2) * xstr + 4 * ct);
        float4 x03 = *(const float4*)(X0 + (4 * k4 + 3) * xstr + 4 * ct);
        float4 x10 = *(const float4*)(X1 + (4 * k4 + 0) * xstr + 4 * ct);
        float4 x11 = *(const float4*)(X1 + (4 * k4 + 1) * xstr + 4 * ct);
        float4 x12 = *(const float4*)(X1 + (4 * k4 + 2) * xstr + 4 * ct);
        float4 x13 = *(const float4*)(X1 + (4 * k4 + 3) * xstr + 4 * ct);
#pragma unroll
        for (int m = 0; m < RPT; m++) {
            float4 av0 = *(const float4*)(Al0 + (rt * RPT + m) * 32 + 4 * k4);
            FMA4(av0.x, x00, acc0[m]);
            FMA4(av0.y, x01, acc0[m]);
            FMA4(av0.z, x02, acc0[m]);
            FMA4(av0.w, x03, acc0[m]);
            float4 av1 = *(const float4*)(Al1 + (rt * RPT + m) * 32 + 4 * k4);
            FMA4(av1.x, x10, acc1[m]);
            FMA4(av1.y, x11, acc1[m]);
            FMA4(av1.z, x12, acc1[m]);
            FMA4(av1.w, x13, acc1[m]);
        }
    }
}

// ---------- gemm_w150_pf: N=150, float2-pair columns ----------
__device__ inline void gemm_w150_pf(const float* Xl, const float* __restrict__ W,
                                    int ct2, int rt2, float acc[5][4], int off23) {
    const float* wp = W + 4 * ct2;
    float2 wa[8], wb[8];
#pragma unroll
    for (int u = 0; u < 8; u++) {
        wa[u] = *(const float2*)(wp + u * 150);
        wb[u] = *(const float2*)(wp + u * 150 + off23);
    }
#pragma unroll 1
    for (int kt = 0; kt < 24; kt++) {
        float2 na[8], nb[8];
#pragma unroll
        for (int u = 0; u < 8; u++) {
            int k = kt * 8 + 8 + u;
            na[u] = *(const float2*)(wp + k * 150);
            nb[u] = *(const float2*)(wp + k * 150 + off23);
        }
#pragma unroll
        for (int m = 0; m < 5; m++) {
            const float* xr = Xl + (rt2 * 5 + m) * FD + kt * 8;
            float4 a0 = *(const float4*)(xr);
            float4 a1 = *(const float4*)(xr + 4);
            float av[8] = {a0.x, a0.y, a0.z, a0.w, a1.x, a1.y, a1.z, a1.w};
#pragma unroll
            for (int u = 0; u < 8; u++) {
                acc[m][0] = fmaf(av[u], wa[u].x, acc[m][0]);
                acc[m][1] = fmaf(av[u], wa[u].y, acc[m][1]);
                acc[m][2] = fmaf(av[u], wb[u].x, acc[m][2]);
                acc[m][3] = fmaf(av[u], wb[u].y, acc[m][3]);
            }
        }
#pragma unroll
        for (int u = 0; u < 8; u++) { wa[u] = na[u]; wb[u] = nb[u]; }
    }
#pragma unroll
    for (int m = 0; m < 5; m++) {
        const float* xr = Xl + (rt2 * 5 + m) * FD + 192;
        float4 a0 = *(const float4*)(xr);
        float4 a1 = *(const float4*)(xr + 4);
        float av[8] = {a0.x, a0.y, a0.z, a0.w, a1.x, a1.y, a1.z, a1.w};
#pragma unroll
        for (int u = 0; u < 8; u++) {
            acc[m][0] = fmaf(av[u], wa[u].x, acc[m][0]);
            acc[m][1] = fmaf(av[u], wa[u].y, acc[m][1]);
            acc[m][2] = fmaf(av[u], wb[u].x, acc[m][2]);
            acc[m][3] = fmaf(av[u], wb[u].y, acc[m][3]);
        }
    }
}

// ================= K2: conv2 fused + F2 = relu(h2 @ Wt + bt) =================
__global__ __launch_bounds__(256) void k_f2(
    const float* __restrict__ C1,
    const float* __restrict__ Wc2, const float* __restrict__ bc2,
    const float* __restrict__ Wt, const float* __restrict__ bt,
    float* __restrict__ F2) {
    const int b = blockIdx.x, t = threadIdx.x;
    __shared__ float buf[S * 130];
    __shared__ float w2l[90 * 32];
    const int ct = t % 50, rt = t / 50;
    const int c3p = t & 63, sg = t >> 6;
    const int p0 = 2 * c3p;

    for (int idx = t; idx < 2700; idx += 256) {
        int ch = idx / 90, r = idx % 90;
        w2l[r * 32 + ch] = Wc2[idx];
    }
    for (int idx = t; idx < 180; idx += 256) {
        int r = idx >> 1, z = idx & 1;
        w2l[r * 32 + 30 + z] = 0.f;
    }
    float bias[8];
#pragma unroll
    for (int m = 0; m < 8; m++) {
        int ch = sg * 8 + m;
        bias[m] = bc2[ch < S ? ch : 0];
    }
    float acc[6][4];
    zacc<6>(acc);

    for (int ks = 0; ks < 8; ks++) {
        for (int idx = t; idx < S * 32; idx += 256) {
            int s = idx >> 5, u = idx & 31;
            float4 v = *(const float4*)(C1 + (size_t)(b * S + s) * TT + ks * 128 + 4 * u);
            float* d = buf + s * 130 + 1 + 4 * u;
            d[0] = v.x; d[1] = v.y; d[2] = v.z; d[3] = v.w;
        }
        if (t < 60) {
            int s = t % S;
            if (t < S) {
                int gt = ks * 128 - 1;
                buf[s * 130] = (gt >= 0) ? C1[(size_t)(b * S + s) * TT + gt] : 0.f;
            } else {
                int gt = ks * 128 + 128;
                buf[s * 130 + 129] = (gt < TT) ? C1[(size_t)(b * S + s) * TT + gt] : 0.f;
            }
        }
        __syncthreads();
        float a0[8], a1[8];
#pragma unroll
        for (int m = 0; m < 8; m++) { a0[m] = bias[m]; a1[m] = bias[m]; }
        for (int si = 0; si < S; si++) {
            float2 va = *(const float2*)(buf + si * 130 + p0);
            float2 vb = *(const float2*)(buf + si * 130 + p0 + 2);
            const float* wr = w2l + si * 96 + sg * 8;
            float4 w0a = *(const float4*)(wr);
            float4 w0b = *(const float4*)(wr + 4);
            float4 w1a = *(const float4*)(wr + 32);
            float4 w1b = *(const float4*)(wr + 36);
            float4 w2a = *(const float4*)(wr + 64);
            float4 w2b = *(const float4*)(wr + 68);
            float w0[8] = {w0a.x, w0a.y, w0a.z, w0a.w, w0b.x, w0b.y, w0b.z, w0b.w};
            float w1[8] = {w1a.x, w1a.y, w1a.z, w1a.w, w1b.x, w1b.y, w1b.z, w1b.w};
            float w2[8] = {w2a.x, w2a.y, w2a.z, w2a.w, w2b.x, w2b.y, w2b.z, w2b.w};
#pragma unroll
            for (int m = 0; m < 8; m++) {
                a0[m] = fmaf(w0[m], va.x, fmaf(w1[m], va.y, fmaf(w2[m], vb.x, a0[m])));
                a1[m] = fmaf(w0[m], va.y, fmaf(w1[m], vb.x, fmaf(w2[m], vb.y, a1[m])));
            }
        }
        __syncthreads();
#pragma unroll
        for (int m = 0; m < 8; m++) {
            int ch = sg * 8 + m;
            if (ch < S) {
                float2 o = {fmaxf(a0[m], 0.f), fmaxf(a1[m], 0.f)};
                *(float2*)(buf + ch * 128 + p0) = o;
            }
        }
        __syncthreads();
        if (t < 250)
            gemm_w4_pf<6, FD, 128>(buf, 128, Wt + (size_t)ks * 128 * FD, ct, rt, acc);
        __syncthreads();
    }
    if (t < 250) {
#pragma unroll
        for (int m = 0; m < 6; m++) {
            int row = rt * 6 + m;
            float4 o;
            o.x = fmaxf(acc[m][0] + bt[4 * ct + 0], 0.f);
            o.y = fmaxf(acc[m][1] + bt[4 * ct + 1], 0.f);
            o.z = fmaxf(acc[m][2] + bt[4 * ct + 2], 0.f);
            o.w = fmaxf(acc[m][3] + bt[4 * ct + 3], 0.f);
            *(float4*)(F2 + (size_t)(b * S + row) * FD + 4 * ct) = o;
        }
    }
}

// ================= K3: k_att = AF + Gv(loc|glb) =================
__global__ __launch_bounds__(256) void k_att(
    const float* __restrict__ F2, const float* __restrict__ Wa,
    const float* __restrict__ adj, const float* __restrict__ Wl,
    const float* __restrict__ Wgl,
    float* __restrict__ AF, float* __restrict__ Gv) {
    const int b = blockIdx.x, t = threadIdx.x;
    __shared__ float A[32 * FD];
    __shared__ float Bu[32 * FD];
    __shared__ float scl[32 * 32];
    __shared__ float adjl[32 * 32];
    for (int idx = t; idx < 32 * FD; idx += 256) {
        A[idx] = (idx < S * FD) ? F2[(size_t)b * S * FD + idx] : 0.f;
        if (idx >= S * FD) Bu[idx] = 0.f;
    }
    for (int idx = t; idx < 1024; idx += 256) {
        int r = idx >> 5, cc = idx & 31;
        adjl[idx] = (r < S && cc < S) ? adj[r * S + cc] : 0.f;
        scl[idx] = 0.f;
    }
    __syncthreads();
    const int ct = t % 50, rt = t / 50;
    float acc[6][4];
    // P = F2 @ Wa -> Bu
    zacc<6>(acc);
    if (t < 250) {
        gemm_w4_pf<6, FD, FD>(A, FD, Wa, ct, rt, acc);
#pragma unroll
        for (int m = 0; m < 6; m++) {
            float4 o = {acc[m][0], acc[m][1], acc[m][2], acc[m][3]};
            *(float4*)(Bu + (rt * 6 + m) * FD + 4 * ct) = o;
        }
    }
    __syncthreads();
    // scl[i,j] = relu(P[i,:] . F2[j,:])
    for (int idx = t; idx < S * S; idx += 256) {
        int i = idx / S, j = idx % S;
        float a = 0.f;
        for (int f4 = 0; f4 < 50; f4++) {
            float4 p = *(const float4*)(Bu + i * FD + 4 * f4);
            float4 q = *(const float4*)(A + j * FD + 4 * f4);
            a = fmaf(p.x, q.x, a); a = fmaf(p.y, q.y, a);
            a = fmaf(p.z, q.z, a); a = fmaf(p.w, q.w, a);
        }
        scl[i * 32 + j] = fmaxf(a, 0.f);
    }
    __syncthreads();
    if (t < S) {
        float mx = -1e30f;
        for (int j = 0; j < S; j++) mx = fmaxf(mx, scl[t * 32 + j]);
        float den = 0.f;
        for (int j = 0; j < S; j++) den += expf(scl[t * 32 + j] - mx);
        float inv = 1.f / den;
        for (int j = 0; j < S; j++) scl[t * 32 + j] = expf(scl[t * 32 + j] - mx) * inv;
    }
    __syncthreads();
    for (int idx = t; idx < S * S; idx += 256)
        AF[(size_t)b * S * S + idx] = scl[(idx / S) * 32 + (idx % S)];
    // loc: T = adj@F2 -> Bu ; Gv[:, :150] = relu(T @ Wl)
    zacc<6>(acc);
    if (t < 250) gemm_a32<6>(adjl, A, FD, ct, rt, acc);
    __syncthreads();
    if (t < 250)
#pragma unroll
        for (int m = 0; m < 6; m++) {
            float4 o = {acc[m][0], acc[m][1], acc[m][2], acc[m][3]};
            *(float4*)(Bu + (rt * 6 + m) * FD + 4 * ct) = o;
        }
    __syncthreads();
    const int ct2 = t % 38, rt2 = t / 38;
    const bool full = (4 * ct2 + 2) < 150;
    const int off23 = full ? 2 : -2;
    if (t < 228) {
        float a2[5][4];
        zacc<5>(a2);
        gemm_w150_pf(Bu, Wl, ct2, rt2, a2, off23);
#pragma unroll
        for (int m = 0; m < 5; m++) {
            float* o = Gv + (size_t)(b * S + rt2 * 5 + m) * 300 + 4 * ct2;
            o[0] = fmaxf(a2[m][0], 0.f); o[1] = fmaxf(a2[m][1], 0.f);
            if (full) { o[2] = fmaxf(a2[m][2], 0.f); o[3] = fmaxf(a2[m][3], 0.f); }
        }
    }
    __syncthreads();
    // glb: T = AF@F2 -> Bu ; Gv[:, 150:] = relu(T @ Wgl)
    zacc<6>(acc);
    if (t < 250) gemm_a32<6>(scl, A, FD, ct, rt, acc);
    __syncthreads();
    if (t < 250)
#pragma unroll
        for (int m = 0; m < 6; m++) {
            float4 o = {acc[m][0], acc[m][1], acc[m][2], acc[m][3]};
            *(float4*)(Bu + (rt * 6 + m) * FD + 4 * ct) = o;
        }
    __syncthreads();
    if (t < 228) {
        float a2[5][4];
        zacc<5>(a2);
        gemm_w150_pf(Bu, Wgl, ct2, rt2, a2, off23);
#pragma unroll
        for (int m = 0; m < 5; m++) {
            float* o = Gv + (size_t)(b * S + rt2 * 5 + m) * 300 + 150 + 4 * ct2;
            o[0] = fmaxf(a2[m][0], 0.f); o[1] = fmaxf(a2[m][1], 0.f);
            if (full) { o[2] = fmaxf(a2[m][2], 0.f); o[3] = fmaxf(a2[m][3], 0.f); }
        }
    }
}

// ================= K4: k_mgcn — 2 samples/block, shared W stream =================
__global__ __launch_bounds__(256, 2) void k_mgcn(
    const float* __restrict__ F2g, const float* __restrict__ AFg,
    const float* __restrict__ adj,
    const float* __restrict__ Wg1, const float* __restrict__ Wg2,
    const float* __restrict__ Wm1, const float* __restrict__ Wm2,
    const float* __restrict__ Wm3, const float* __restrict__ wg,
    const float* __restrict__ Wp1, const float* __restrict__ Wp2,
    const float* __restrict__ Wp3,
    float* __restrict__ Rws, float* __restrict__ Gh) {
    const int b0 = blockIdx.x * 2, b1 = b0 + 1;
    const int t = threadIdx.x;
    __shared__ float A0[32 * FD], A1[32 * FD];
    __shared__ float afl0[1024], afl1[1024];
    __shared__ float adjl[1024];
    __shared__ float sk[192];
    __shared__ float gl[192];
    const int ct = t % 50, rt = t / 50;
    const int ct3 = t % 25, rt3 = t / 25;

    for (int idx = t; idx < 1500; idx += 256) {
        *(float4*)(A0 + 4 * idx) = *(const float4*)(F2g + (size_t)b0 * S * FD + 4 * idx);
        *(float4*)(A1 + 4 * idx) = *(const float4*)(F2g + (size_t)b1 * S * FD + 4 * idx);
    }
    for (int idx = t; idx < 400; idx += 256) { A0[6000 + idx] = 0.f; A1[6000 + idx] = 0.f; }
    for (int idx = t; idx < 1024; idx += 256) {
        int r = idx >> 5, cc = idx & 31;
        bool in = (r < S && cc < S);
        afl0[idx] = in ? AFg[(size_t)b0 * S * S + r * S + cc] : 0.f;
        afl1[idx] = in ? AFg[(size_t)b1 * S * S + r * S + cc] : 0.f;
        adjl[idx] = in ? adj[r * S + cc] : 0.f;
    }
    if (t < 192) sk[t] = 0.f;
    __syncthreads();

    float acc0[6][4], acc1[6][4], xsr0[6][4], xsr1[6][4];

#define DZ() { zacc<6>(acc0); zacc<6>(acc1); }
#define DWRITE(RELU)                                                        \
    if (t < 250) {                                                          \
        _Pragma("unroll")                                                   \
        for (int m = 0; m < 6; m++) {                                       \
            float4 o0, o1;                                                  \
            o0.x = RELU ? fmaxf(acc0[m][0], 0.f) : acc0[m][0];              \
            o0.y = RELU ? fmaxf(acc0[m][1], 0.f) : acc0[m][1];              \
            o0.z = RELU ? fmaxf(acc0[m][2], 0.f) : acc0[m][2];              \
            o0.w = RELU ? fmaxf(acc0[m][3], 0.f) : acc0[m][3];              \
            o1.x = RELU ? fmaxf(acc1[m][0], 0.f) : acc1[m][0];              \
            o1.y = RELU ? fmaxf(acc1[m][1], 0.f) : acc1[m][1];              \
            o1.z = RELU ? fmaxf(acc1[m][2], 0.f) : acc1[m][2];              \
            o1.w = RELU ? fmaxf(acc1[m][3], 0.f) : acc1[m][3];              \
            *(float4*)(A0 + (rt * 6 + m) * FD + 4 * ct) = o0;               \
            *(float4*)(A1 + (rt * 6 + m) * FD + 4 * ct) = o1;               \
        }                                                                   \
    }

    // ---- xs chain, in place (destroys F2 in A0/A1) ----
    DZ();
    if (t < 250) gemm_a32_dual<6>(adjl, A0, adjl, A1, FD, ct, rt, acc0, acc1);
    __syncthreads();
    DWRITE(false);
    __syncthreads();
    DZ();
    if (t < 250) gemm_w4_pf_dual<6, FD, FD>(A0, A1, FD, Wg1, ct, rt, acc0, acc1);
    __syncthreads();
    DWRITE(true);
    __syncthreads();
    DZ();
    if (t < 250) gemm_a32_dual<6>(adjl, A0, adjl, A1, FD, ct, rt, acc0, acc1);
    __syncthreads();
    DWRITE(false);
    __syncthreads();
    DZ();
    if (t < 250) gemm_w4_pf_dual<6, FD, FD>(A0, A1, FD, Wg2, ct, rt, acc0, acc1);
    __syncthreads();   // all reads of A=T2 done
#pragma unroll
    for (int m = 0; m < 6; m++) {
#pragma unroll
        for (int q = 0; q < 4; q++) { xsr0[m][q] = acc0[m][q]; xsr1[m][q] = acc1[m][q]; }
    }
    for (int idx = t; idx < 1500; idx += 256) {
        *(float4*)(A0 + 4 * idx) = *(const float4*)(F2g + (size_t)b0 * S * FD + 4 * idx);
        *(float4*)(A1 + 4 * idx) = *(const float4*)(F2g + (size_t)b1 * S * FD + 4 * idx);
    }
    __syncthreads();

    // ---- MGCN chain: k = 0,1,2 ----
    const float* Wm[3] = {Wm1, Wm2, Wm3};
    const float* Wp[3] = {Wp1, Wp2, Wp3};
#pragma unroll 1
    for (int k = 0; k < 3; k++) {
        // T = AF @ X
        DZ();
        if (t < 250) gemm_a32_dual<6>(afl0, A0, afl1, A1, FD, ct, rt, acc0, acc1);
        __syncthreads();
        DWRITE(false);
        __syncthreads();
        // X_k = relu(T @ Wm_k) in regs
        DZ();
        if (t < 250) gemm_w4_pf_dual<6, FD, FD>(A0, A1, FD, Wm[k], ct, rt, acc0, acc1);
        __syncthreads();   // reads of A=T done
        if (t < 250) {
#pragma unroll
            for (int m = 0; m < 6; m++) {
#pragma unroll
                for (int q = 0; q < 4; q++) {
                    acc0[m][q] = fmaxf(acc0[m][q], 0.f);
                    acc1[m][q] = fmaxf(acc1[m][q], 0.f);
                }
            }
#pragma unroll
            for (int m = 0; m < 6; m++) {
                int row = rt * 6 + m;
                float wg0 = wg[(4 * ct + 0) * 3 + k], wg1v = wg[(4 * ct + 1) * 3 + k];
                float wg2v = wg[(4 * ct + 2) * 3 + k], wg3 = wg[(4 * ct + 3) * 3 + k];
                float h00 = 0.5f * (acc0[m][0] + xsr0[m][0]);
                float h01 = 0.5f * (acc0[m][1] + xsr0[m][1]);
                float h02 = 0.5f * (acc0[m][2] + xsr0[m][2]);
                float h03 = 0.5f * (acc0[m][3] + xsr0[m][3]);
                float4 o0 = {h00, h01, h02, h03};
                *(float4*)(A0 + row * FD + 4 * ct) = o0;
                atomicAdd(&sk[row * 3 + k],
                          h00 * wg0 + h01 * wg1v + h02 * wg2v + h03 * wg3);
                float h10 = 0.5f * (acc1[m][0] + xsr1[m][0]);
                float h11 = 0.5f * (acc1[m][1] + xsr1[m][1]);
                float h12 = 0.5f * (acc1[m][2] + xsr1[m][2]);
                float h13 = 0.5f * (acc1[m][3] + xsr1[m][3]);
                float4 o1 = {h10, h11, h12, h13};
                *(float4*)(A1 + row * FD + 4 * ct) = o1;
                atomicAdd(&sk[96 + row * 3 + k],
                          h10 * wg0 + h11 * wg1v + h12 * wg2v + h13 * wg3);
            }
        }
        __syncthreads();
        // R_k = H_k @ Wp_k -> workspace
        if (t < 250) {
            float a30[3][4], a31[3][4];
            zacc<3>(a30); zacc<3>(a31);
            gemm_w4_pf_dual<3, 100, FD>(A0, A1, FD, Wp[k], ct3, rt3, a30, a31);
#pragma unroll
            for (int m = 0; m < 3; m++) {
                float4 o0 = {a30[m][0], a30[m][1], a30[m][2], a30[m][3]};
                float4 o1 = {a31[m][0], a31[m][1], a31[m][2], a31[m][3]};
                *(float4*)(Rws + ((size_t)(k * BB + b0) * S + rt3 * 3 + m) * 100 + 4 * ct3) = o0;
                *(float4*)(Rws + ((size_t)(k * BB + b1) * S + rt3 * 3 + m) * 100 + 4 * ct3) = o1;
            }
        }
        __syncthreads();   // reads of A=H_k done
        if (k < 2) {
            DWRITE(false);   // acc already relu'd: restore X_k
            __syncthreads();
        }
    }

    // ---- gates ----
    if (t < S) {
        float a0 = sk[t * 3 + 0], a1 = sk[t * 3 + 1], a2 = sk[t * 3 + 2];
        float m = fmaxf(a0, fmaxf(a1, a2));
        float e0 = expf(a0 - m), e1 = expf(a1 - m), e2 = expf(a2 - m);
        float inv = 1.f / (e0 + e1 + e2);
        gl[t * 3 + 0] = e0 * inv; gl[t * 3 + 1] = e1 * inv; gl[t * 3 + 2] = e2 * inv;
    } else if (t >= 64 && t < 64 + S) {
        int s = t - 64;
        float a0 = sk[96 + s * 3 + 0], a1 = sk[96 + s * 3 + 1], a2 = sk[96 + s * 3 + 2];
        float m = fmaxf(a0, fmaxf(a1, a2));
        float e0 = expf(a0 - m), e1 = expf(a1 - m), e2 = expf(a2 - m);
        float inv = 1.f / (e0 + e1 + e2);
        gl[96 + s * 3 + 0] = e0 * inv; gl[96 + s * 3 + 1] = e1 * inv; gl[96 + s * 3 + 2] = e2 * inv;
    }
    __syncthreads();

    // ---- G_k = adj @ diag(g_k) @ R_k ----
#pragma unroll 1
    for (int k = 0; k < 3; k++) {
        for (int idx = t; idx < S * 100; idx += 256) {
            int row = idx / 100, col = idx % 100;
            A0[row * FD + col] = Rws[((size_t)(k * BB + b0) * S) * 100 + idx];
            A1[row * FD + col] = Rws[((size_t)(k * BB + b1) * S) * 100 + idx];
        }
        for (int idx = t; idx < 1024; idx += 256) {
            int cc = idx & 31;
            afl0[idx] = (cc < S) ? adjl[idx] * gl[cc * 3 + k] : 0.f;
            afl1[idx] = (cc < S) ? adjl[idx] * gl[96 + cc * 3 + k] : 0.f;
        }
        __syncthreads();
        if (t < 250) {
            float a30[3][4], a31[3][4];
            zacc<3>(a30); zacc<3>(a31);
            gemm_a32_dual<3>(afl0, A0, afl1, A1, FD, ct3, rt3, a30, a31);
#pragma unroll
            for (int m = 0; m < 3; m++) {
                float4 o0 = {a30[m][0], a30[m][1], a30[m][2], a30[m][3]};
                float4 o1 = {a31[m][0], a31[m][1], a31[m][2], a31[m][3]};
                *(float4*)(Gh + (size_t)(b0 * S + rt3 * 3 + m) * 300 + k * 100 + 4 * ct3) = o0;
                *(float4*)(Gh + (size_t)(b1 * S + rt3 * 3 + m) * 300 + k * 100 + 4 * ct3) = o1;
            }
        }
        __syncthreads();
    }
#undef DZ
#undef DWRITE
}

// ================= K5: transpose Wcls -> WclsT[c][i] (once) =================
// NOTE: writes into the C1-overlay region -> must launch AFTER k_f2.
__global__ __launch_bounds__(256) void k_tw(const float* __restrict__ Wcls,
                                            float* __restrict__ WclsT) {
    int idx = blockIdx.x * 256 + threadIdx.x;
    if (idx < S * 600 * NC) {
        int i = idx / NC, c = idx % NC;
        WclsT[c * (S * 600) + i] = Wcls[idx];
    }
}

// ================= K6: fused SE gates + classifier + log_softmax =================
__global__ __launch_bounds__(256) void k_secls(
    const float* __restrict__ Gh, const float* __restrict__ Gv,
    const float* __restrict__ Ws1, const float* __restrict__ Ws2,
    const float* __restrict__ Wf1, const float* __restrict__ Wf2,
    const float* __restrict__ WclsT, const float* __restrict__ bcls,
    float* __restrict__ out) {
    const int b = blockIdx.x, t = threadIdx.x;
    __shared__ float red[NC][256];
    __shared__ float mrow[S];
    __shared__ float u[15];
    __shared__ float mb[300];
    __shared__ float v[150];
    __shared__ float wftl[300];
    __shared__ float wchl[S];
    // ---- phase 1: SE gates (was k_se), gates land in LDS ----
    if (t < S) {
        float a = 0.f;
        const float* gp = Gv + ((size_t)b * S + t) * 300;
        for (int j = 0; j < 300; j++) a += gp[j];
        mrow[t] = a * (1.f / 300.f);
    }
    for (int j = t; j < 300; j += 256) {
        float a = 0.f;
        for (int s = 0; s < S; s++) a += Gh[(size_t)b * S * 300 + s * 300 + j];
        mb[j] = a * (1.f / S);
    }
    __syncthreads();
    if (t < 15) {
        float a = 0.f;
        for (int i = 0; i < S; i++) a += mrow[i] * Ws1[i * 15 + t];
        u[t] = fmaxf(a, 0.f);
    }
    if (t >= 64 && t < 64 + 150) {
        int h = t - 64;
        float a = 0.f;
        for (int j = 0; j < 300; j++) a += mb[j] * Wf1[j * 150 + h];
        v[h] = fmaxf(a, 0.f);
    }
    __syncthreads();
    if (t < S) {
        float a = 0.f;
        for (int h = 0; h < 15; h++) a += u[h] * Ws2[h * 30 + t];
        wchl[t] = 1.f / (1.f + expf(-a));
    }
    for (int j = t; j < 300; j += 256) {
        float a = 0.f;
        for (int h = 0; h < 150; h++) a += v[h] * Wf2[h * 300 + j];
        wftl[j] = 1.f / (1.f + expf(-a));
    }
    __syncthreads();
    // ---- phase 2: classifier with transposed weights (coalesced) ----
    float acc[NC];
#pragma unroll
    for (int c = 0; c < NC; c++) acc[c] = 0.f;
    for (int i = t; i < S * 600; i += 256) {
        int s = i / 600, j = i % 600;
        float gval = (j < 300)
            ? Gh[(size_t)b * S * 300 + s * 300 + j] * wchl[s]
            : Gv[(size_t)b * S * 300 + s * 300 + (j - 300)] * wftl[j - 300];
#pragma unroll
        for (int c = 0; c < NC; c++)
            acc[c] = fmaf(gval, WclsT[c * (S * 600) + i], acc[c]);
    }
#pragma unroll
    for (int c = 0; c < NC; c++) red[c][t] = acc[c];
    __syncthreads();
    for (int off = 128; off > 0; off >>= 1) {
        if (t < off) {
#pragma unroll
            for (int c = 0; c < NC; c++) red[c][t] += red[c][t + off];
        }
        __syncthreads();
    }
    if (t == 0) {
        float lg[NC];
        float mx = -1e30f;
#pragma unroll
        for (int c = 0; c < NC; c++) { lg[c] = red[c][0] + bcls[c]; mx = fmaxf(mx, lg[c]); }
        float den = 0.f;
#pragma unroll
        for (int c = 0; c < NC; c++) den += expf(lg[c] - mx);
        float lden = logf(den) + mx;
#pragma unroll
        for (int c = 0; c < NC; c++) out[b * NC + c] = lg[c] - lden;
    }
}

extern "C" void kernel_launch(void* const* d_in, const int* in_sizes, int n_in,
                              void* d_out, int out_size, void* d_ws, size_t ws_size,
                              hipStream_t stream) {
    const float* x    = (const float*)d_in[0];
    const float* adj  = (const float*)d_in[1];
    const float* Wc1  = (const float*)d_in[2];
    const float* bc1  = (const float*)d_in[3];
    const float* Wc2  = (const float*)d_in[4];
    const float* bc2  = (const float*)d_in[5];
    const float* Wt   = (const float*)d_in[6];
    const float* bt   = (const float*)d_in[7];
    const float* Wa   = (const float*)d_in[8];
    const float* Wm1  = (const float*)d_in[9];
    const float* Wm2  = (const float*)d_in[10];
    const float* Wm3  = (const float*)d_in[11];
    const float* Wg1  = (const float*)d_in[12];
    const float* Wg2  = (const float*)d_in[13];
    const float* wg   = (const float*)d_in[14];
    const float* Wp1  = (const float*)d_in[15];
    const float* Wp2  = (const float*)d_in[16];
    const float* Wp3  = (const float*)d_in[17];
    const float* Wl   = (const float*)d_in[18];
    const float* Wgl  = (const float*)d_in[19];
    const float* Ws1  = (const float*)d_in[20];
    const float* Ws2  = (const float*)d_in[21];
    const float* Wf1  = (const float*)d_in[22];
    const float* Wf2  = (const float*)d_in[23];
    const float* Wcls = (const float*)d_in[24];
    const float* bcls = (const float*)d_in[25];

    float* ws    = (float*)d_ws;
    float* C1    = ws + OFS_C1;
    float* F2    = ws + OFS_F2;
    float* AF    = ws + OFS_AF;
    float* GV    = ws + OFS_GV;
    float* GH    = ws + OFS_GH;
    float* RWS   = ws + OFS_R;
    float* WCLST = ws + OFS_WT;
    float* out   = (float*)d_out;

    k_conv1<<<dim3(4, BB), 256, 0, stream>>>(x, Wc1, bc1, C1);
    k_f2<<<BB, 256, 0, stream>>>(C1, Wc2, bc2, Wt, bt, F2);
    // k_tw writes into the (now dead) C1 overlay region -> must follow k_f2.
    k_tw<<<(S * 600 * NC + 255) / 256, 256, 0, stream>>>(Wcls, WCLST);
    k_att<<<BB, 256, 0, stream>>>(F2, Wa, adj, Wl, Wgl, AF, GV);
    k_mgcn<<<BB / 2, 256, 0, stream>>>(F2, AF, adj, Wg1, Wg2, Wm1, Wm2, Wm3, wg,
                                       Wp1, Wp2, Wp3, RWS, GH);
    k_secls<<<BB, 256, 0, stream>>>(GH, GV, Ws1, Ws2, Wf1, Wf2, WCLST, bcls, out);
}

// Round 8
// 1131.859 us; speedup vs baseline: 1.1154x; 1.0133x over previous
//
#include <hip/hip_runtime.h>
#include <math.h>

#define S   30
#define FD  200
#define TT  1024
#define BB  1024
#define NC  7

// ---- workspace layout (float offsets), overlaid by live range ----
// C1 occupies [0, 31457280) and is LIVE until k_f2 completes.
// AF/GV/GH/RWS/WclsT overlay the C1 region and may only be written AFTER k_f2.
#define OFS_C1   0ull
#define OFS_F2   31457280ull
#define OFS_AF   0ull
#define OFS_GV   921600ull
#define OFS_GH   10137600ull
#define OFS_R    19691520ull     // 3*1024*30*100 floats
#define OFS_WT   28907520ull     // WclsT: 7*18000 = 126,000 floats

// ================= K1: conv1 + relu -> C1 =================
__global__ __launch_bounds__(256) void k_conv1(
    const float* __restrict__ x,
    const float* __restrict__ Wc1, const float* __restrict__ bc1,
    float* __restrict__ C1) {
    const int c = blockIdx.x, b = blockIdx.y;
    const int t = threadIdx.x;
    const int t0 = c * 256;
    __shared__ float xb[S * 258];
    __shared__ float w1l[90 * 32];
    for (int idx = t; idx < 2700; idx += 256) {
        int so = idx / 90, r = idx % 90;
        w1l[r * 32 + so] = Wc1[idx];
    }
    for (int idx = t; idx < 180; idx += 256) {
        int r = idx >> 1, z = idx & 1;
        w1l[r * 32 + 30 + z] = 0.f;
    }
    for (int idx = t; idx < S * 64; idx += 256) {
        int s = idx >> 6, u = idx & 63;
        float4 v = *(const float4*)(x + (size_t)(b * S + s) * TT + t0 + 4 * u);
        float* d = xb + s * 258 + 1 + 4 * u;
        d[0] = v.x; d[1] = v.y; d[2] = v.z; d[3] = v.w;
    }
    if (t < 60) {
        int s = t % S;
        if (t < S) {
            int gt = t0 - 1;
            xb[s * 258] = (gt >= 0) ? x[(size_t)(b * S + s) * TT + gt] : 0.f;
        } else {
            int gt = t0 + 256;
            xb[s * 258 + 257] = (gt < TT) ? x[(size_t)(b * S + s) * TT + gt] : 0.f;
        }
    }
    __syncthreads();
    float acc[32];
#pragma unroll
    for (int so = 0; so < 32; so++) acc[so] = (so < S) ? bc1[so] : 0.f;
    for (int si = 0; si < S; si++) {
        float v0 = xb[si * 258 + t];
        float v1 = xb[si * 258 + t + 1];
        float v2 = xb[si * 258 + t + 2];
        const float* wr = w1l + si * 96;
#pragma unroll
        for (int u = 0; u < 8; u++) {
            float4 w0 = *(const float4*)(wr + 4 * u);
            float4 w1 = *(const float4*)(wr + 32 + 4 * u);
            float4 w2 = *(const float4*)(wr + 64 + 4 * u);
            acc[4 * u + 0] = fmaf(w0.x, v0, fmaf(w1.x, v1, fmaf(w2.x, v2, acc[4 * u + 0])));
            acc[4 * u + 1] = fmaf(w0.y, v0, fmaf(w1.y, v1, fmaf(w2.y, v2, acc[4 * u + 1])));
            acc[4 * u + 2] = fmaf(w0.z, v0, fmaf(w1.z, v1, fmaf(w2.z, v2, acc[4 * u + 2])));
            acc[4 * u + 3] = fmaf(w0.w, v0, fmaf(w1.w, v1, fmaf(w2.w, v2, acc[4 * u + 3])));
        }
    }
#pragma unroll
    for (int so = 0; so < 32; so++) {
        if (so < S)
            C1[(size_t)(b * S + so) * TT + t0 + t] = fmaxf(acc[so], 0.f);
    }
}

// ---------- FMA tile helpers ----------
#define FMA4(av, wv, accm)                           \
    {                                                \
        accm[0] = fmaf(av, (wv).x, accm[0]);         \
        accm[1] = fmaf(av, (wv).y, accm[1]);         \
        accm[2] = fmaf(av, (wv).z, accm[2]);         \
        accm[3] = fmaf(av, (wv).w, accm[3]);         \
    }

__device__ inline void fma_tile8(const float4 a0, const float4 a1,
                                 const float4 w[8], float accm[4]) {
    FMA4(a0.x, w[0], accm); FMA4(a0.y, w[1], accm);
    FMA4(a0.z, w[2], accm); FMA4(a0.w, w[3], accm);
    FMA4(a1.x, w[4], accm); FMA4(a1.y, w[5], accm);
    FMA4(a1.z, w[6], accm); FMA4(a1.w, w[7], accm);
}

template<int RPT>
__device__ inline void zacc(float acc[][4]) {
#pragma unroll
    for (int m = 0; m < RPT; m++)
#pragma unroll
        for (int q = 0; q < 4; q++) acc[m][q] = 0.f;
}

// ---------- gemm_w4_pf: X(LDS) @ W(global), depth-8 register pipeline ----------
template<int RPT, int N, int K>
__device__ inline void gemm_w4_pf(const float* Xl, int xstr, const float* __restrict__ W,
                                  int ct, int rt, float acc[][4]) {
    const float* wp = W + 4 * ct;
    float4 wreg[8];
#pragma unroll
    for (int u = 0; u < 8; u++) wreg[u] = *(const float4*)(wp + u * N);
#pragma unroll 1
    for (int kt = 0; kt < K / 8 - 1; kt++) {
        float4 wnxt[8];
#pragma unroll
        for (int u = 0; u < 8; u++) wnxt[u] = *(const float4*)(wp + (kt * 8 + 8 + u) * N);
#pragma unroll
        for (int m = 0; m < RPT; m++) {
            const float* xr = Xl + (rt * RPT + m) * xstr + kt * 8;
            float4 a0 = *(const float4*)(xr);
            float4 a1 = *(const float4*)(xr + 4);
            fma_tile8(a0, a1, wreg, acc[m]);
        }
#pragma unroll
        for (int u = 0; u < 8; u++) wreg[u] = wnxt[u];
    }
    {
        const int kb = K - 8;
#pragma unroll
        for (int m = 0; m < RPT; m++) {
            const float* xr = Xl + (rt * RPT + m) * xstr + kb;
            float4 a0 = *(const float4*)(xr);
            float4 a1 = *(const float4*)(xr + 4);
            fma_tile8(a0, a1, wreg, acc[m]);
        }
    }
}

// ---------- gemm_w4_pf_dual: shared W stream, two X buffers / acc sets ----------
template<int RPT, int N, int K>
__device__ inline void gemm_w4_pf_dual(const float* X0, const float* X1, int xstr,
                                       const float* __restrict__ W,
                                       int ct, int rt,
                                       float acc0[][4], float acc1[][4]) {
    const float* wp = W + 4 * ct;
    float4 wreg[8];
#pragma unroll
    for (int u = 0; u < 8; u++) wreg[u] = *(const float4*)(wp + u * N);
#pragma unroll 1
    for (int kt = 0; kt < K / 8 - 1; kt++) {
        float4 wnxt[8];
#pragma unroll
        for (int u = 0; u < 8; u++) wnxt[u] = *(const float4*)(wp + (kt * 8 + 8 + u) * N);
#pragma unroll
        for (int m = 0; m < RPT; m++) {
            const float* xr = X0 + (rt * RPT + m) * xstr + kt * 8;
            float4 a0 = *(const float4*)(xr);
            float4 a1 = *(const float4*)(xr + 4);
            fma_tile8(a0, a1, wreg, acc0[m]);
        }
#pragma unroll
        for (int m = 0; m < RPT; m++) {
            const float* xr = X1 + (rt * RPT + m) * xstr + kt * 8;
            float4 a0 = *(const float4*)(xr);
            float4 a1 = *(const float4*)(xr + 4);
            fma_tile8(a0, a1, wreg, acc1[m]);
        }
#pragma unroll
        for (int u = 0; u < 8; u++) wreg[u] = wnxt[u];
    }
    {
        const int kb = K - 8;
#pragma unroll
        for (int m = 0; m < RPT; m++) {
            const float* xr = X0 + (rt * RPT + m) * xstr + kb;
            float4 a0 = *(const float4*)(xr);
            float4 a1 = *(const float4*)(xr + 4);
            fma_tile8(a0, a1, wreg, acc0[m]);
        }
#pragma unroll
        for (int m = 0; m < RPT; m++) {
            const float* xr = X1 + (rt * RPT + m) * xstr + kb;
            float4 a0 = *(const float4*)(xr);
            float4 a1 = *(const float4*)(xr + 4);
            fma_tile8(a0, a1, wreg, acc1[m]);
        }
    }
}

// ---------- gemm_a32: Al(LDS, stride 32) @ Xl(LDS) ----------
template<int RPT>
__device__ inline void gemm_a32(const float* Al, const float* Xl, int xstr,
                                int ct, int rt, float acc[][4]) {
#pragma unroll
    for (int k4 = 0; k4 < 8; k4++) {
        float4 xv0 = *(const float4*)(Xl + (4 * k4 + 0) * xstr + 4 * ct);
        float4 xv1 = *(const float4*)(Xl + (4 * k4 + 1) * xstr + 4 * ct);
        float4 xv2 = *(const float4*)(Xl + (4 * k4 + 2) * xstr + 4 * ct);
        float4 xv3 = *(const float4*)(Xl + (4 * k4 + 3) * xstr + 4 * ct);
#pragma unroll
        for (int m = 0; m < RPT; m++) {
            float4 av = *(const float4*)(Al + (rt * RPT + m) * 32 + 4 * k4);
            FMA4(av.x, xv0, acc[m]);
            FMA4(av.y, xv1, acc[m]);
            FMA4(av.z, xv2, acc[m]);
            FMA4(av.w, xv3, acc[m]);
        }
    }
}

// ---------- gemm_a32_dual ----------
template<int RPT>
__device__ inline void gemm_a32_dual(const float* Al0, const float* X0,
                                     const float* Al1, const float* X1,
                                     int xstr, int ct, int rt,
                                     float acc0[][4], float acc1[][4]) {
#pragma unroll
    for (int k4 = 0; k4 < 8; k4++) {
        float4 x00 = *(const float4*)(X0 + (4 * k4 + 0) * xstr + 4 * ct);
        float4 x01 = *(const float4*)(X0 + (4 * k4 + 1) * xstr + 4 * ct);
        float4 x02 = *(const float4*)(X0 + (4 * k4 + 2) * xstr + 4 * ct);
        float4 x03 = *(const float4*)(X0 + (4 * k4 + 3) * xstr + 4 * ct);
        float4 x10 = *(const float4*)(X1 + (4 * k4 + 0) * xstr + 4 * ct);
        float4 x11 = *(const float4*)(X1 + (4 * k4 + 1) * xstr + 4 * ct);
        float4 x12 = *(const float4*)(X1 + (4 * k4 + 2) * xstr + 4 * ct);
        float4 x13 = *(const float4*)(X1 + (4 * k4 + 3) * xstr + 4 * ct);
#pragma unroll
        for (int m = 0; m < RPT; m++) {
            float4 av0 = *(const float4*)(Al0 + (rt * RPT + m) * 32 + 4 * k4);
            FMA4(av0.x, x00, acc0[m]);
            FMA4(av0.y, x01, acc0[m]);
            FMA4(av0.z, x02, acc0[m]);
            FMA4(av0.w, x03, acc0[m]);
            float4 av1 = *(const float4*)(Al1 + (rt * RPT + m) * 32 + 4 * k4);
            FMA4(av1.x, x10, acc1[m]);
            FMA4(av1.y, x11, acc1[m]);
            FMA4(av1.z, x12, acc1[m]);
            FMA4(av1.w, x13, acc1[m]);
        }
    }
}

// ---------- gemm_w150_pf: N=150, float2-pair columns ----------
__device__ inline void gemm_w150_pf(const float* Xl, const float* __restrict__ W,
                                    int ct2, int rt2, float acc[5][4], int off23) {
    const float* wp = W + 4 * ct2;
    float2 wa[8], wb[8];
#pragma unroll
    for (int u = 0; u < 8; u++) {
        wa[u] = *(const float2*)(wp + u * 150);
        wb[u] = *(const float2*)(wp + u * 150 + off23);
    }
#pragma unroll 1
    for (int kt = 0; kt < 24; kt++) {
        float2 na[8], nb[8];
#pragma unroll
        for (int u = 0; u < 8; u++) {
            int k = kt * 8 + 8 + u;
            na[u] = *(const float2*)(wp + k * 150);
            nb[u] = *(const float2*)(wp + k * 150 + off23);
        }
#pragma unroll
        for (int m = 0; m < 5; m++) {
            const float* xr = Xl + (rt2 * 5 + m) * FD + kt * 8;
            float4 a0 = *(const float4*)(xr);
            float4 a1 = *(const float4*)(xr + 4);
            float av[8] = {a0.x, a0.y, a0.z, a0.w, a1.x, a1.y, a1.z, a1.w};
#pragma unroll
            for (int u = 0; u < 8; u++) {
                acc[m][0] = fmaf(av[u], wa[u].x, acc[m][0]);
                acc[m][1] = fmaf(av[u], wa[u].y, acc[m][1]);
                acc[m][2] = fmaf(av[u], wb[u].x, acc[m][2]);
                acc[m][3] = fmaf(av[u], wb[u].y, acc[m][3]);
            }
        }
#pragma unroll
        for (int u = 0; u < 8; u++) { wa[u] = na[u]; wb[u] = nb[u]; }
    }
#pragma unroll
    for (int m = 0; m < 5; m++) {
        const float* xr = Xl + (rt2 * 5 + m) * FD + 192;
        float4 a0 = *(const float4*)(xr);
        float4 a1 = *(const float4*)(xr + 4);
        float av[8] = {a0.x, a0.y, a0.z, a0.w, a1.x, a1.y, a1.z, a1.w};
#pragma unroll
        for (int u = 0; u < 8; u++) {
            acc[m][0] = fmaf(av[u], wa[u].x, acc[m][0]);
            acc[m][1] = fmaf(av[u], wa[u].y, acc[m][1]);
            acc[m][2] = fmaf(av[u], wb[u].x, acc[m][2]);
            acc[m][3] = fmaf(av[u], wb[u].y, acc[m][3]);
        }
    }
}

// ---------- gemm_w150_pf_dual: shared W stream, two X buffers / acc sets ----------
__device__ inline void gemm_w150_pf_dual(const float* X0, const float* X1,
                                         const float* __restrict__ W,
                                         int ct2, int rt2,
                                         float acc0[5][4], float acc1[5][4], int off23) {
    const float* wp = W + 4 * ct2;
    float2 wa[8], wb[8];
#pragma unroll
    for (int u = 0; u < 8; u++) {
        wa[u] = *(const float2*)(wp + u * 150);
        wb[u] = *(const float2*)(wp + u * 150 + off23);
    }
#pragma unroll 1
    for (int kt = 0; kt < 24; kt++) {
        float2 na[8], nb[8];
#pragma unroll
        for (int u = 0; u < 8; u++) {
            int k = kt * 8 + 8 + u;
            na[u] = *(const float2*)(wp + k * 150);
            nb[u] = *(const float2*)(wp + k * 150 + off23);
        }
#pragma unroll
        for (int m = 0; m < 5; m++) {
            const float* xr = X0 + (rt2 * 5 + m) * FD + kt * 8;
            float4 a0 = *(const float4*)(xr);
            float4 a1 = *(const float4*)(xr + 4);
            float av[8] = {a0.x, a0.y, a0.z, a0.w, a1.x, a1.y, a1.z, a1.w};
#pragma unroll
            for (int u = 0; u < 8; u++) {
                acc0[m][0] = fmaf(av[u], wa[u].x, acc0[m][0]);
                acc0[m][1] = fmaf(av[u], wa[u].y, acc0[m][1]);
                acc0[m][2] = fmaf(av[u], wb[u].x, acc0[m][2]);
                acc0[m][3] = fmaf(av[u], wb[u].y, acc0[m][3]);
            }
        }
#pragma unroll
        for (int m = 0; m < 5; m++) {
            const float* xr = X1 + (rt2 * 5 + m) * FD + kt * 8;
            float4 a0 = *(const float4*)(xr);
            float4 a1 = *(const float4*)(xr + 4);
            float av[8] = {a0.x, a0.y, a0.z, a0.w, a1.x, a1.y, a1.z, a1.w};
#pragma unroll
            for (int u = 0; u < 8; u++) {
                acc1[m][0] = fmaf(av[u], wa[u].x, acc1[m][0]);
                acc1[m][1] = fmaf(av[u], wa[u].y, acc1[m][1]);
                acc1[m][2] = fmaf(av[u], wb[u].x, acc1[m][2]);
                acc1[m][3] = fmaf(av[u], wb[u].y, acc1[m][3]);
            }
        }
#pragma unroll
        for (int u = 0; u < 8; u++) { wa[u] = na[u]; wb[u] = nb[u]; }
    }
#pragma unroll
    for (int m = 0; m < 5; m++) {
        const float* xr = X0 + (rt2 * 5 + m) * FD + 192;
        float4 a0 = *(const float4*)(xr);
        float4 a1 = *(const float4*)(xr + 4);
        float av[8] = {a0.x, a0.y, a0.z, a0.w, a1.x, a1.y, a1.z, a1.w};
#pragma unroll
        for (int u = 0; u < 8; u++) {
            acc0[m][0] = fmaf(av[u], wa[u].x, acc0[m][0]);
            acc0[m][1] = fmaf(av[u], wa[u].y, acc0[m][1]);
            acc0[m][2] = fmaf(av[u], wb[u].x, acc0[m][2]);
            acc0[m][3] = fmaf(av[u], wb[u].y, acc0[m][3]);
        }
    }
#pragma unroll
    for (int m = 0; m < 5; m++) {
        const float* xr = X1 + (rt2 * 5 + m) * FD + 192;
        float4 a0 = *(const float4*)(xr);
        float4 a1 = *(const float4*)(xr + 4);
        float av[8] = {a0.x, a0.y, a0.z, a0.w, a1.x, a1.y, a1.z, a1.w};
#pragma unroll
        for (int u = 0; u < 8; u++) {
            acc1[m][0] = fmaf(av[u], wa[u].x, acc1[m][0]);
            acc1[m][1] = fmaf(av[u], wa[u].y, acc1[m][1]);
            acc1[m][2] = fmaf(av[u], wb[u].x, acc1[m][2]);
            acc1[m][3] = fmaf(av[u], wb[u].y, acc1[m][3]);
        }
    }
}

// ================= K2: conv2 fused + F2 = relu(h2 @ Wt + bt) =================
__global__ __launch_bounds__(256) void k_f2(
    const float* __restrict__ C1,
    const float* __restrict__ Wc2, const float* __restrict__ bc2,
    const float* __restrict__ Wt, const float* __restrict__ bt,
    float* __restrict__ F2) {
    const int b = blockIdx.x, t = threadIdx.x;
    __shared__ float buf[S * 130];
    __shared__ float w2l[90 * 32];
    const int ct = t % 50, rt = t / 50;
    const int c3p = t & 63, sg = t >> 6;
    const int p0 = 2 * c3p;

    for (int idx = t; idx < 2700; idx += 256) {
        int ch = idx / 90, r = idx % 90;
        w2l[r * 32 + ch] = Wc2[idx];
    }
    for (int idx = t; idx < 180; idx += 256) {
        int r = idx >> 1, z = idx & 1;
        w2l[r * 32 + 30 + z] = 0.f;
    }
    float bias[8];
#pragma unroll
    for (int m = 0; m < 8; m++) {
        int ch = sg * 8 + m;
        bias[m] = bc2[ch < S ? ch : 0];
    }
    float acc[6][4];
    zacc<6>(acc);

    for (int ks = 0; ks < 8; ks++) {
        for (int idx = t; idx < S * 32; idx += 256) {
            int s = idx >> 5, u = idx & 31;
            float4 v = *(const float4*)(C1 + (size_t)(b * S + s) * TT + ks * 128 + 4 * u);
            float* d = buf + s * 130 + 1 + 4 * u;
            d[0] = v.x; d[1] = v.y; d[2] = v.z; d[3] = v.w;
        }
        if (t < 60) {
            int s = t % S;
            if (t < S) {
                int gt = ks * 128 - 1;
                buf[s * 130] = (gt >= 0) ? C1[(size_t)(b * S + s) * TT + gt] : 0.f;
            } else {
                int gt = ks * 128 + 128;
                buf[s * 130 + 129] = (gt < TT) ? C1[(size_t)(b * S + s) * TT + gt] : 0.f;
            }
        }
        __syncthreads();
        float a0[8], a1[8];
#pragma unroll
        for (int m = 0; m < 8; m++) { a0[m] = bias[m]; a1[m] = bias[m]; }
        for (int si = 0; si < S; si++) {
            float2 va = *(const float2*)(buf + si * 130 + p0);
            float2 vb = *(const float2*)(buf + si * 130 + p0 + 2);
            const float* wr = w2l + si * 96 + sg * 8;
            float4 w0a = *(const float4*)(wr);
            float4 w0b = *(const float4*)(wr + 4);
            float4 w1a = *(const float4*)(wr + 32);
            float4 w1b = *(const float4*)(wr + 36);
            float4 w2a = *(const float4*)(wr + 64);
            float4 w2b = *(const float4*)(wr + 68);
            float w0[8] = {w0a.x, w0a.y, w0a.z, w0a.w, w0b.x, w0b.y, w0b.z, w0b.w};
            float w1[8] = {w1a.x, w1a.y, w1a.z, w1a.w, w1b.x, w1b.y, w1b.z, w1b.w};
            float w2[8] = {w2a.x, w2a.y, w2a.z, w2a.w, w2b.x, w2b.y, w2b.z, w2b.w};
#pragma unroll
            for (int m = 0; m < 8; m++) {
                a0[m] = fmaf(w0[m], va.x, fmaf(w1[m], va.y, fmaf(w2[m], vb.x, a0[m])));
                a1[m] = fmaf(w0[m], va.y, fmaf(w1[m], vb.x, fmaf(w2[m], vb.y, a1[m])));
            }
        }
        __syncthreads();
#pragma unroll
        for (int m = 0; m < 8; m++) {
            int ch = sg * 8 + m;
            if (ch < S) {
                float2 o = {fmaxf(a0[m], 0.f), fmaxf(a1[m], 0.f)};
                *(float2*)(buf + ch * 128 + p0) = o;
            }
        }
        __syncthreads();
        if (t < 250)
            gemm_w4_pf<6, FD, 128>(buf, 128, Wt + (size_t)ks * 128 * FD, ct, rt, acc);
        __syncthreads();
    }
    if (t < 250) {
#pragma unroll
        for (int m = 0; m < 6; m++) {
            int row = rt * 6 + m;
            float4 o;
            o.x = fmaxf(acc[m][0] + bt[4 * ct + 0], 0.f);
            o.y = fmaxf(acc[m][1] + bt[4 * ct + 1], 0.f);
            o.z = fmaxf(acc[m][2] + bt[4 * ct + 2], 0.f);
            o.w = fmaxf(acc[m][3] + bt[4 * ct + 3], 0.f);
            *(float4*)(F2 + (size_t)(b * S + row) * FD + 4 * ct) = o;
        }
    }
}

// ================= K3: k_att2 — dual-sample, shared W register streams =================
// r4's only verified structural win (register-level W-sharing) applied to k_att.
// LDS ≈ 114.7 KB -> 1 block/CU (4 waves, 1/SIMD): deliberately tests whether the
// wave-insensitivity seen at 2-4 waves/SIMD (r1/r3/r4) extends to 1/SIMD.
__global__ __launch_bounds__(256) void k_att2(
    const float* __restrict__ F2, const float* __restrict__ Wa,
    const float* __restrict__ adj, const float* __restrict__ Wl,
    const float* __restrict__ Wgl,
    float* __restrict__ AF, float* __restrict__ Gv) {
    const int b0 = blockIdx.x * 2, b1 = b0 + 1;
    const int t = threadIdx.x;
    __shared__ float A0[32 * FD], A1[32 * FD];    // F2 per sample, rows 30/31 zero
    __shared__ float Bu0[32 * FD], Bu1[32 * FD];  // P / T staging per sample
    __shared__ float scl0[1024], scl1[1024];      // scores -> A_F (stride 32)
    __shared__ float adjl[1024];
    for (int idx = t; idx < 1500; idx += 256) {
        *(float4*)(A0 + 4 * idx) = *(const float4*)(F2 + (size_t)b0 * S * FD + 4 * idx);
        *(float4*)(A1 + 4 * idx) = *(const float4*)(F2 + (size_t)b1 * S * FD + 4 * idx);
    }
    for (int idx = t; idx < 400; idx += 256) {
        A0[6000 + idx] = 0.f; A1[6000 + idx] = 0.f;
        Bu0[6000 + idx] = 0.f; Bu1[6000 + idx] = 0.f;
    }
    for (int idx = t; idx < 1024; idx += 256) {
        int r = idx >> 5, cc = idx & 31;
        adjl[idx] = (r < S && cc < S) ? adj[r * S + cc] : 0.f;
        scl0[idx] = 0.f; scl1[idx] = 0.f;
    }
    __syncthreads();
    const int ct = t % 50, rt = t / 50;
    float acc0[6][4], acc1[6][4];
    // P = F2 @ Wa (dual, shared W stream) -> Bu
    zacc<6>(acc0); zacc<6>(acc1);
    if (t < 250) {
        gemm_w4_pf_dual<6, FD, FD>(A0, A1, FD, Wa, ct, rt, acc0, acc1);
#pragma unroll
        for (int m = 0; m < 6; m++) {
            float4 o0 = {acc0[m][0], acc0[m][1], acc0[m][2], acc0[m][3]};
            float4 o1 = {acc1[m][0], acc1[m][1], acc1[m][2], acc1[m][3]};
            *(float4*)(Bu0 + (rt * 6 + m) * FD + 4 * ct) = o0;
            *(float4*)(Bu1 + (rt * 6 + m) * FD + 4 * ct) = o1;
        }
    }
    __syncthreads();
    // scl[i,j] = relu(P[i,:] . F2[j,:]) for both samples (1800 dots)
    for (int idx = t; idx < 2 * S * S; idx += 256) {
        int h = idx / (S * S), r = idx % (S * S);
        int i = r / S, j = r % S;
        const float* Pb = h ? Bu1 : Bu0;
        const float* Fb = h ? A1 : A0;
        float a = 0.f;
        for (int f4 = 0; f4 < 50; f4++) {
            float4 p = *(const float4*)(Pb + i * FD + 4 * f4);
            float4 q = *(const float4*)(Fb + j * FD + 4 * f4);
            a = fmaf(p.x, q.x, a); a = fmaf(p.y, q.y, a);
            a = fmaf(p.z, q.z, a); a = fmaf(p.w, q.w, a);
        }
        float* sc = h ? scl1 : scl0;
        sc[i * 32 + j] = fmaxf(a, 0.f);
    }
    __syncthreads();
    // softmax rows: lanes 0..29 -> sample0, lanes 64..93 -> sample1
    if (t < S) {
        float mx = -1e30f;
        for (int j = 0; j < S; j++) mx = fmaxf(mx, scl0[t * 32 + j]);
        float den = 0.f;
        for (int j = 0; j < S; j++) den += expf(scl0[t * 32 + j] - mx);
        float inv = 1.f / den;
        for (int j = 0; j < S; j++) scl0[t * 32 + j] = expf(scl0[t * 32 + j] - mx) * inv;
    } else if (t >= 64 && t < 64 + S) {
        int s = t - 64;
        float mx = -1e30f;
        for (int j = 0; j < S; j++) mx = fmaxf(mx, scl1[s * 32 + j]);
        float den = 0.f;
        for (int j = 0; j < S; j++) den += expf(scl1[s * 32 + j] - mx);
        float inv = 1.f / den;
        for (int j = 0; j < S; j++) scl1[s * 32 + j] = expf(scl1[s * 32 + j] - mx) * inv;
    }
    __syncthreads();
    for (int idx = t; idx < S * S; idx += 256) {
        int i = idx / S, j = idx % S;
        AF[(size_t)b0 * S * S + idx] = scl0[i * 32 + j];
        AF[(size_t)b1 * S * S + idx] = scl1[i * 32 + j];
    }
    // loc: T = adj@F2 (dual) -> Bu ; Gv[:, :150] = relu(T @ Wl) (dual W stream)
    zacc<6>(acc0); zacc<6>(acc1);
    if (t < 250) gemm_a32_dual<6>(adjl, A0, adjl, A1, FD, ct, rt, acc0, acc1);
    __syncthreads();
    if (t < 250) {
#pragma unroll
        for (int m = 0; m < 6; m++) {
            float4 o0 = {acc0[m][0], acc0[m][1], acc0[m][2], acc0[m][3]};
            float4 o1 = {acc1[m][0], acc1[m][1], acc1[m][2], acc1[m][3]};
            *(float4*)(Bu0 + (rt * 6 + m) * FD + 4 * ct) = o0;
            *(float4*)(Bu1 + (rt * 6 + m) * FD + 4 * ct) = o1;
        }
    }
    __syncthreads();
    const int ct2 = t % 38, rt2 = t / 38;
    const bool full = (4 * ct2 + 2) < 150;
    const int off23 = full ? 2 : -2;
    if (t < 228) {
        float a20[5][4], a21[5][4];
        zacc<5>(a20); zacc<5>(a21);
        gemm_w150_pf_dual(Bu0, Bu1, Wl, ct2, rt2, a20, a21, off23);
#pragma unroll
        for (int m = 0; m < 5; m++) {
            float* o0 = Gv + (size_t)(b0 * S + rt2 * 5 + m) * 300 + 4 * ct2;
            float* o1 = Gv + (size_t)(b1 * S + rt2 * 5 + m) * 300 + 4 * ct2;
            o0[0] = fmaxf(a20[m][0], 0.f); o0[1] = fmaxf(a20[m][1], 0.f);
            o1[0] = fmaxf(a21[m][0], 0.f); o1[1] = fmaxf(a21[m][1], 0.f);
            if (full) {
                o0[2] = fmaxf(a20[m][2], 0.f); o0[3] = fmaxf(a20[m][3], 0.f);
                o1[2] = fmaxf(a21[m][2], 0.f); o1[3] = fmaxf(a21[m][3], 0.f);
            }
        }
    }
    __syncthreads();
    // glb: T = AF@F2 (dual) -> Bu ; Gv[:, 150:] = relu(T @ Wgl) (dual W stream)
    zacc<6>(acc0); zacc<6>(acc1);
    if (t < 250) gemm_a32_dual<6>(scl0, A0, scl1, A1, FD, ct, rt, acc0, acc1);
    __syncthreads();
    if (t < 250) {
#pragma unroll
        for (int m = 0; m < 6; m++) {
            float4 o0 = {acc0[m][0], acc0[m][1], acc0[m][2], acc0[m][3]};
            float4 o1 = {acc1[m][0], acc1[m][1], acc1[m][2], acc1[m][3]};
            *(float4*)(Bu0 + (rt * 6 + m) * FD + 4 * ct) = o0;
            *(float4*)(Bu1 + (rt * 6 + m) * FD + 4 * ct) = o1;
        }
    }
    __syncthreads();
    if (t < 228) {
        float a20[5][4], a21[5][4];
        zacc<5>(a20); zacc<5>(a21);
        gemm_w150_pf_dual(Bu0, Bu1, Wgl, ct2, rt2, a20, a21, off23);
#pragma unroll
        for (int m = 0; m < 5; m++) {
            float* o0 = Gv + (size_t)(b0 * S + rt2 * 5 + m) * 300 + 150 + 4 * ct2;
            float* o1 = Gv + (size_t)(b1 * S + rt2 * 5 + m) * 300 + 150 + 4 * ct2;
            o0[0] = fmaxf(a20[m][0], 0.f); o0[1] = fmaxf(a20[m][1], 0.f);
            o1[0] = fmaxf(a21[m][0], 0.f); o1[1] = fmaxf(a21[m][1], 0.f);
            if (full) {
                o0[2] = fmaxf(a20[m][2], 0.f); o0[3] = fmaxf(a20[m][3], 0.f);
                o1[2] = fmaxf(a21[m][2], 0.f); o1[3] = fmaxf(a21[m][3], 0.f);
            }
        }
    }
}

// ================= K4: k_mgcn — 2 samples/block, shared W stream =================
__global__ __launch_bounds__(256, 2) void k_mgcn(
    const float* __restrict__ F2g, const float* __restrict__ AFg,
    const float* __restrict__ adj,
    const float* __restrict__ Wg1, const float* __restrict__ Wg2,
    const float* __restrict__ Wm1, const float* __restrict__ Wm2,
    const float* __restrict__ Wm3, const float* __restrict__ wg,
    const float* __restrict__ Wp1, const float* __restrict__ Wp2,
    const float* __restrict__ Wp3,
    float* __restrict__ Rws, float* __restrict__ Gh) {
    const int b0 = blockIdx.x * 2, b1 = b0 + 1;
    const int t = threadIdx.x;
    __shared__ float A0[32 * FD], A1[32 * FD];
    __shared__ float afl0[1024], afl1[1024];
    __shared__ float adjl[1024];
    __shared__ float sk[192];
    __shared__ float gl[192];
    const int ct = t % 50, rt = t / 50;
    const int ct3 = t % 25, rt3 = t / 25;

    for (int idx = t; idx < 1500; idx += 256) {
        *(float4*)(A0 + 4 * idx) = *(const float4*)(F2g + (size_t)b0 * S * FD + 4 * idx);
        *(float4*)(A1 + 4 * idx) = *(const float4*)(F2g + (size_t)b1 * S * FD + 4 * idx);
    }
    for (int idx = t; idx < 400; idx += 256) { A0[6000 + idx] = 0.f; A1[6000 + idx] = 0.f; }
    for (int idx = t; idx < 1024; idx += 256) {
        int r = idx >> 5, cc = idx & 31;
        bool in = (r < S && cc < S);
        afl0[idx] = in ? AFg[(size_t)b0 * S * S + r * S + cc] : 0.f;
        afl1[idx] = in ? AFg[(size_t)b1 * S * S + r * S + cc] : 0.f;
        adjl[idx] = in ? adj[r * S + cc] : 0.f;
    }
    if (t < 192) sk[t] = 0.f;
    __syncthreads();

    float acc0[6][4], acc1[6][4], xsr0[6][4], xsr1[6][4];

#define DZ() { zacc<6>(acc0); zacc<6>(acc1); }
#define DWRITE(RELU)                                                        \
    if (t < 250) {                                                          \
        _Pragma("unroll")                                                   \
        for (int m = 0; m < 6; m++) {                                       \
            float4 o0, o1;                                                  \
            o0.x = RELU ? fmaxf(acc0[m][0], 0.f) : acc0[m][0];              \
            o0.y = RELU ? fmaxf(acc0[m][1], 0.f) : acc0[m][1];              \
            o0.z = RELU ? fmaxf(acc0[m][2], 0.f) : acc0[m][2];              \
            o0.w = RELU ? fmaxf(acc0[m][3], 0.f) : acc0[m][3];              \
            o1.x = RELU ? fmaxf(acc1[m][0], 0.f) : acc1[m][0];              \
            o1.y = RELU ? fmaxf(acc1[m][1], 0.f) : acc1[m][1];              \
            o1.z = RELU ? fmaxf(acc1[m][2], 0.f) : acc1[m][2];              \
            o1.w = RELU ? fmaxf(acc1[m][3], 0.f) : acc1[m][3];              \
            *(float4*)(A0 + (rt * 6 + m) * FD + 4 * ct) = o0;               \
            *(float4*)(A1 + (rt * 6 + m) * FD + 4 * ct) = o1;               \
        }                                                                   \
    }

    // ---- xs chain, in place (destroys F2 in A0/A1) ----
    DZ();
    if (t < 250) gemm_a32_dual<6>(adjl, A0, adjl, A1, FD, ct, rt, acc0, acc1);
    __syncthreads();
    DWRITE(false);
    __syncthreads();
    DZ();
    if (t < 250) gemm_w4_pf_dual<6, FD, FD>(A0, A1, FD, Wg1, ct, rt, acc0, acc1);
    __syncthreads();
    DWRITE(true);
    __syncthreads();
    DZ();
    if (t < 250) gemm_a32_dual<6>(adjl, A0, adjl, A1, FD, ct, rt, acc0, acc1);
    __syncthreads();
    DWRITE(false);
    __syncthreads();
    DZ();
    if (t < 250) gemm_w4_pf_dual<6, FD, FD>(A0, A1, FD, Wg2, ct, rt, acc0, acc1);
    __syncthreads();   // all reads of A=T2 done
#pragma unroll
    for (int m = 0; m < 6; m++) {
#pragma unroll
        for (int q = 0; q < 4; q++) { xsr0[m][q] = acc0[m][q]; xsr1[m][q] = acc1[m][q]; }
    }
    for (int idx = t; idx < 1500; idx += 256) {
        *(float4*)(A0 + 4 * idx) = *(const float4*)(F2g + (size_t)b0 * S * FD + 4 * idx);
        *(float4*)(A1 + 4 * idx) = *(const float4*)(F2g + (size_t)b1 * S * FD + 4 * idx);
    }
    __syncthreads();

    // ---- MGCN chain: k = 0,1,2 ----
    const float* Wm[3] = {Wm1, Wm2, Wm3};
    const float* Wp[3] = {Wp1, Wp2, Wp3};
#pragma unroll 1
    for (int k = 0; k < 3; k++) {
        // T = AF @ X
        DZ();
        if (t < 250) gemm_a32_dual<6>(afl0, A0, afl1, A1, FD, ct, rt, acc0, acc1);
        __syncthreads();
        DWRITE(false);
        __syncthreads();
        // X_k = relu(T @ Wm_k) in regs
        DZ();
        if (t < 250) gemm_w4_pf_dual<6, FD, FD>(A0, A1, FD, Wm[k], ct, rt, acc0, acc1);
        __syncthreads();   // reads of A=T done
        if (t < 250) {
#pragma unroll
            for (int m = 0; m < 6; m++) {
#pragma unroll
                for (int q = 0; q < 4; q++) {
                    acc0[m][q] = fmaxf(acc0[m][q], 0.f);
                    acc1[m][q] = fmaxf(acc1[m][q], 0.f);
                }
            }
#pragma unroll
            for (int m = 0; m < 6; m++) {
                int row = rt * 6 + m;
                float wg0 = wg[(4 * ct + 0) * 3 + k], wg1v = wg[(4 * ct + 1) * 3 + k];
                float wg2v = wg[(4 * ct + 2) * 3 + k], wg3 = wg[(4 * ct + 3) * 3 + k];
                float h00 = 0.5f * (acc0[m][0] + xsr0[m][0]);
                float h01 = 0.5f * (acc0[m][1] + xsr0[m][1]);
                float h02 = 0.5f * (acc0[m][2] + xsr0[m][2]);
                float h03 = 0.5f * (acc0[m][3] + xsr0[m][3]);
                float4 o0 = {h00, h01, h02, h03};
                *(float4*)(A0 + row * FD + 4 * ct) = o0;
                atomicAdd(&sk[row * 3 + k],
                          h00 * wg0 + h01 * wg1v + h02 * wg2v + h03 * wg3);
                float h10 = 0.5f * (acc1[m][0] + xsr1[m][0]);
                float h11 = 0.5f * (acc1[m][1] + xsr1[m][1]);
                float h12 = 0.5f * (acc1[m][2] + xsr1[m][2]);
                float h13 = 0.5f * (acc1[m][3] + xsr1[m][3]);
                float4 o1 = {h10, h11, h12, h13};
                *(float4*)(A1 + row * FD + 4 * ct) = o1;
                atomicAdd(&sk[96 + row * 3 + k],
                          h10 * wg0 + h11 * wg1v + h12 * wg2v + h13 * wg3);
            }
        }
        __syncthreads();
        // R_k = H_k @ Wp_k -> workspace
        if (t < 250) {
            float a30[3][4], a31[3][4];
            zacc<3>(a30); zacc<3>(a31);
            gemm_w4_pf_dual<3, 100, FD>(A0, A1, FD, Wp[k], ct3, rt3, a30, a31);
#pragma unroll
            for (int m = 0; m < 3; m++) {
                float4 o0 = {a30[m][0], a30[m][1], a30[m][2], a30[m][3]};
                float4 o1 = {a31[m][0], a31[m][1], a31[m][2], a31[m][3]};
                *(float4*)(Rws + ((size_t)(k * BB + b0) * S + rt3 * 3 + m) * 100 + 4 * ct3) = o0;
                *(float4*)(Rws + ((size_t)(k * BB + b1) * S + rt3 * 3 + m) * 100 + 4 * ct3) = o1;
            }
        }
        __syncthreads();   // reads of A=H_k done
        if (k < 2) {
            DWRITE(false);   // acc already relu'd: restore X_k
            __syncthreads();
        }
    }

    // ---- gates ----
    if (t < S) {
        float a0 = sk[t * 3 + 0], a1 = sk[t * 3 + 1], a2 = sk[t * 3 + 2];
        float m = fmaxf(a0, fmaxf(a1, a2));
        float e0 = expf(a0 - m), e1 = expf(a1 - m), e2 = expf(a2 - m);
        float inv = 1.f / (e0 + e1 + e2);
        gl[t * 3 + 0] = e0 * inv; gl[t * 3 + 1] = e1 * inv; gl[t * 3 + 2] = e2 * inv;
    } else if (t >= 64 && t < 64 + S) {
        int s = t - 64;
        float a0 = sk[96 + s * 3 + 0], a1 = sk[96 + s * 3 + 1], a2 = sk[96 + s * 3 + 2];
        float m = fmaxf(a0, fmaxf(a1, a2));
        float e0 = expf(a0 - m), e1 = expf(a1 - m), e2 = expf(a2 - m);
        float inv = 1.f / (e0 + e1 + e2);
        gl[96 + s * 3 + 0] = e0 * inv; gl[96 + s * 3 + 1] = e1 * inv; gl[96 + s * 3 + 2] = e2 * inv;
    }
    __syncthreads();

    // ---- G_k = adj @ diag(g_k) @ R_k ----
#pragma unroll 1
    for (int k = 0; k < 3; k++) {
        for (int idx = t; idx < S * 100; idx += 256) {
            int row = idx / 100, col = idx % 100;
            A0[row * FD + col] = Rws[((size_t)(k * BB + b0) * S) * 100 + idx];
            A1[row * FD + col] = Rws[((size_t)(k * BB + b1) * S) * 100 + idx];
        }
        for (int idx = t; idx < 1024; idx += 256) {
            int cc = idx & 31;
            afl0[idx] = (cc < S) ? adjl[idx] * gl[cc * 3 + k] : 0.f;
            afl1[idx] = (cc < S) ? adjl[idx] * gl[96 + cc * 3 + k] : 0.f;
        }
        __syncthreads();
        if (t < 250) {
            float a30[3][4], a31[3][4];
            zacc<3>(a30); zacc<3>(a31);
            gemm_a32_dual<3>(afl0, A0, afl1, A1, FD, ct3, rt3, a30, a31);
#pragma unroll
            for (int m = 0; m < 3; m++) {
                float4 o0 = {a30[m][0], a30[m][1], a30[m][2], a30[m][3]};
                float4 o1 = {a31[m][0], a31[m][1], a31[m][2], a31[m][3]};
                *(float4*)(Gh + (size_t)(b0 * S + rt3 * 3 + m) * 300 + k * 100 + 4 * ct3) = o0;
                *(float4*)(Gh + (size_t)(b1 * S + rt3 * 3 + m) * 300 + k * 100 + 4 * ct3) = o1;
            }
        }
        __syncthreads();
    }
#undef DZ
#undef DWRITE
}

// ================= K5: transpose Wcls -> WclsT[c][i] (once) =================
// NOTE: writes into the C1-overlay region -> must launch AFTER k_f2.
__global__ __launch_bounds__(256) void k_tw(const float* __restrict__ Wcls,
                                            float* __restrict__ WclsT) {
    int idx = blockIdx.x * 256 + threadIdx.x;
    if (idx < S * 600 * NC) {
        int i = idx / NC, c = idx % NC;
        WclsT[c * (S * 600) + i] = Wcls[idx];
    }
}

// ================= K6: fused SE gates + classifier + log_softmax =================
__global__ __launch_bounds__(256) void k_secls(
    const float* __restrict__ Gh, const float* __restrict__ Gv,
    const float* __restrict__ Ws1, const float* __restrict__ Ws2,
    const float* __restrict__ Wf1, const float* __restrict__ Wf2,
    const float* __restrict__ WclsT, const float* __restrict__ bcls,
    float* __restrict__ out) {
    const int b = blockIdx.x, t = threadIdx.x;
    __shared__ float red[NC][256];
    __shared__ float mrow[S];
    __shared__ float u[15];
    __shared__ float mb[300];
    __shared__ float v[150];
    __shared__ float wftl[300];
    __shared__ float wchl[S];
    if (t < S) {
        float a = 0.f;
        const float* gp = Gv + ((size_t)b * S + t) * 300;
        for (int j = 0; j < 300; j++) a += gp[j];
        mrow[t] = a * (1.f / 300.f);
    }
    for (int j = t; j < 300; j += 256) {
        float a = 0.f;
        for (int s = 0; s < S; s++) a += Gh[(size_t)b * S * 300 + s * 300 + j];
        mb[j] = a * (1.f / S);
    }
    __syncthreads();
    if (t < 15) {
        float a = 0.f;
        for (int i = 0; i < S; i++) a += mrow[i] * Ws1[i * 15 + t];
        u[t] = fmaxf(a, 0.f);
    }
    if (t >= 64 && t < 64 + 150) {
        int h = t - 64;
        float a = 0.f;
        for (int j = 0; j < 300; j++) a += mb[j] * Wf1[j * 150 + h];
        v[h] = fmaxf(a, 0.f);
    }
    __syncthreads();
    if (t < S) {
        float a = 0.f;
        for (int h = 0; h < 15; h++) a += u[h] * Ws2[h * 30 + t];
        wchl[t] = 1.f / (1.f + expf(-a));
    }
    for (int j = t; j < 300; j += 256) {
        float a = 0.f;
        for (int h = 0; h < 150; h++) a += v[h] * Wf2[h * 300 + j];
        wftl[j] = 1.f / (1.f + expf(-a));
    }
    __syncthreads();
    float acc[NC];
#pragma unroll
    for (int c = 0; c < NC; c++) acc[c] = 0.f;
    for (int i = t; i < S * 600; i += 256) {
        int s = i / 600, j = i % 600;
        float gval = (j < 300)
            ? Gh[(size_t)b * S * 300 + s * 300 + j] * wchl[s]
            : Gv[(size_t)b * S * 300 + s * 300 + (j - 300)] * wftl[j - 300];
#pragma unroll
        for (int c = 0; c < NC; c++)
            acc[c] = fmaf(gval, WclsT[c * (S * 600) + i], acc[c]);
    }
#pragma unroll
    for (int c = 0; c < NC; c++) red[c][t] = acc[c];
    __syncthreads();
    for (int off = 128; off > 0; off >>= 1) {
        if (t < off) {
#pragma unroll
            for (int c = 0; c < NC; c++) red[c][t] += red[c][t + off];
        }
        __syncthreads();
    }
    if (t == 0) {
        float lg[NC];
        float mx = -1e30f;
#pragma unroll
        for (int c = 0; c < NC; c++) { lg[c] = red[c][0] + bcls[c]; mx = fmaxf(mx, lg[c]); }
        float den = 0.f;
#pragma unroll
        for (int c = 0; c < NC; c++) den += expf(lg[c] - mx);
        float lden = logf(den) + mx;
#pragma unroll
        for (int c = 0; c < NC; c++) out[b * NC + c] = lg[c] - lden;
    }
}

extern "C" void kernel_launch(void* const* d_in, const int* in_sizes, int n_in,
                              void* d_out, int out_size, void* d_ws, size_t ws_size,
                              hipStream_t stream) {
    const float* x    = (const float*)d_in[0];
    const float* adj  = (const float*)d_in[1];
    const float* Wc1  = (const float*)d_in[2];
    const float* bc1  = (const float*)d_in[3];
    const float* Wc2  = (const float*)d_in[4];
    const float* bc2  = (const float*)d_in[5];
    const float* Wt   = (const float*)d_in[6];
    const float* bt   = (const float*)d_in[7];
    const float* Wa   = (const float*)d_in[8];
    const float* Wm1  = (const float*)d_in[9];
    const float* Wm2  = (const float*)d_in[10];
    const float* Wm3  = (const float*)d_in[11];
    const float* Wg1  = (const float*)d_in[12];
    const float* Wg2  = (const float*)d_in[13];
    const float* wg   = (const float*)d_in[14];
    const float* Wp1  = (const float*)d_in[15];
    const float* Wp2  = (const float*)d_in[16];
    const float* Wp3  = (const float*)d_in[17];
    const float* Wl   = (const float*)d_in[18];
    const float* Wgl  = (const float*)d_in[19];
    const float* Ws1  = (const float*)d_in[20];
    const float* Ws2  = (const float*)d_in[21];
    const float* Wf1  = (const float*)d_in[22];
    const float* Wf2  = (const float*)d_in[23];
    const float* Wcls = (const float*)d_in[24];
    const float* bcls = (const float*)d_in[25];

    float* ws    = (float*)d_ws;
    float* C1    = ws + OFS_C1;
    float* F2    = ws + OFS_F2;
    float* AF    = ws + OFS_AF;
    float* GV    = ws + OFS_GV;
    float* GH    = ws + OFS_GH;
    float* RWS   = ws + OFS_R;
    float* WCLST = ws + OFS_WT;
    float* out   = (float*)d_out;

    k_conv1<<<dim3(4, BB), 256, 0, stream>>>(x, Wc1, bc1, C1);
    k_f2<<<BB, 256, 0, stream>>>(C1, Wc2, bc2, Wt, bt, F2);
    // k_tw writes into the (now dead) C1 overlay region -> must follow k_f2.
    k_tw<<<(S * 600 * NC + 255) / 256, 256, 0, stream>>>(Wcls, WCLST);
    k_att2<<<BB / 2, 256, 0, stream>>>(F2, Wa, adj, Wl, Wgl, AF, GV);
    k_mgcn<<<BB / 2, 256, 0, stream>>>(F2, AF, adj, Wg1, Wg2, Wm1, Wm2, Wm3, wg,
                                       Wp1, Wp2, Wp3, RWS, GH);
    k_secls<<<BB, 256, 0, stream>>>(GH, GV, Ws1, Ws2, Wf1, Wf2, WCLST, bcls, out);
}